// Round 1
// baseline (403.012 us; speedup 1.0000x reference)
//
#include <hip/hip_runtime.h>
#include <hip/hip_bf16.h>
#include <float.h>

#define B 4
#define D 256
#define HH 112
#define WW 112
#define WS 7
#define NW 256
#define LL 49
#define TOPK 8
#define NH 8
#define DH 32
#define PADR 132   // LDS row stride (floats) for 128-ch tiles: 16B-aligned, bank-spread

__device__ __forceinline__ float elu1(float x) {
    // elu(x)+1 : x>0 -> x+1 ; else exp(x)
    return x > 0.f ? x + 1.f : __expf(x);
}

// ---------------------------------------------------------------------------
// K1: per-window means of q,k,v. One block per (b,c); thread = window (16x16).
// Writes qm[b][w][c], kmf=elu(km)+1 [b][w][c], vm[b][w][c], kmT[b][c][w].
// ---------------------------------------------------------------------------
__global__ __launch_bounds__(256) void k_means(
        const float* __restrict__ q, const float* __restrict__ k,
        const float* __restrict__ v, float* __restrict__ qm,
        float* __restrict__ kmf, float* __restrict__ vm,
        float* __restrict__ kmT) {
    int b = blockIdx.x >> 8;
    int c = blockIdx.x & 255;
    int w = threadIdx.x;            // window index
    int wi = w >> 4, wj = w & 15;
    size_t base = (size_t)(b * D + c) * (HH * WW);
    int off0 = (wi * WS) * WW + wj * WS;
    float sq = 0.f, sk = 0.f, sv = 0.f;
    for (int r = 0; r < WS; ++r) {
        int o = off0 + r * WW;
        for (int x = 0; x < WS; ++x) {
            sq += q[base + o + x];
            sk += k[base + o + x];
            sv += v[base + o + x];
        }
    }
    const float inv = 1.f / 49.f;
    sq *= inv; sk *= inv; sv *= inv;
    qm [(size_t)(b * NW + w) * D + c] = sq;
    kmf[(size_t)(b * NW + w) * D + c] = elu1(sk);
    vm [(size_t)(b * NW + w) * D + c] = sv;
    kmT[(size_t)(b * D + c) * NW + w] = sk;
}

// ---------------------------------------------------------------------------
// K2: sim row + top-8. One block per (b,qw); thread t = key-window.
// ---------------------------------------------------------------------------
__global__ __launch_bounds__(256) void k_topk(
        const float* __restrict__ qm, const float* __restrict__ kmT,
        int* __restrict__ idx) {
    __shared__ float qrow[D];
    __shared__ float sv[NW];
    __shared__ float rv[NW];
    __shared__ int   ri[NW];
    int b = blockIdx.x >> 8;
    int qw = blockIdx.x & 255;
    int t = threadIdx.x;
    qrow[t] = qm[(size_t)(b * NW + qw) * D + t];
    __syncthreads();
    float acc = 0.f;
    const float* kb = kmT + (size_t)b * D * NW + t;
    for (int d = 0; d < D; ++d) acc += qrow[d] * kb[(size_t)d * NW];
    sv[t] = acc;
    __syncthreads();
    for (int sel = 0; sel < TOPK; ++sel) {
        rv[t] = sv[t]; ri[t] = t;
        __syncthreads();
        for (int s = 128; s > 0; s >>= 1) {
            if (t < s) {
                if (rv[t + s] > rv[t]) { rv[t] = rv[t + s]; ri[t] = ri[t + s]; }
            }
            __syncthreads();
        }
        if (t == 0) {
            idx[(size_t)(b * NW + qw) * TOPK + sel] = ri[0];
            sv[ri[0]] = -FLT_MAX;
        }
        __syncthreads();
    }
}

// ---------------------------------------------------------------------------
// K3: per-(b,win,half) KVw[h][32][32] = sum_l Kf[l] (x) V[l], Ksw = sum_l Kf.
// Stage 49x128 k/v tiles in LDS (elu applied to k at store), 4x4 reg tiling.
// ---------------------------------------------------------------------------
__global__ __launch_bounds__(256) void k_kvw(
        const float* __restrict__ k, const float* __restrict__ v,
        float* __restrict__ KVw, float* __restrict__ Ksw) {
    __shared__ float kf[LL * PADR];
    __shared__ float vf[LL * PADR];
    int blk = blockIdx.x;
    int b = blk >> 9;
    int win = (blk >> 1) & 255;
    int half = blk & 1;
    int wi = win >> 4, wj = win & 15;
    int t = threadIdx.x;
    for (int tens = 0; tens < 2; ++tens) {
        const float* src = tens ? v : k;
        float* dst = tens ? vf : kf;
        for (int p = t; p < 128 * WS; p += 256) {
            int c = p / WS, r = p % WS;
            int C = half * 128 + c;
            size_t g = ((size_t)((b * D + C) * HH + wi * WS + r)) * WW + wj * WS;
            for (int x = 0; x < WS; ++x) {
                float val = src[g + x];
                if (tens == 0) val = elu1(val);
                dst[(r * WS + x) * PADR + c] = val;
            }
        }
    }
    __syncthreads();
    int h2 = t >> 6;            // sub-head 0..3
    int q64 = t & 63;
    int ddq = q64 >> 3, dvq = q64 & 7;
    int ab = h2 * 32 + ddq * 4;
    int bb = h2 * 32 + dvq * 4;
    float acc[4][4] = {};
    float ks[4] = {};
    for (int l = 0; l < LL; ++l) {
        float4 a  = *(const float4*)&kf[l * PADR + ab];
        float4 bv = *(const float4*)&vf[l * PADR + bb];
        float av[4] = {a.x, a.y, a.z, a.w};
        float bw[4] = {bv.x, bv.y, bv.z, bv.w};
        ks[0] += av[0]; ks[1] += av[1]; ks[2] += av[2]; ks[3] += av[3];
        for (int i = 0; i < 4; ++i)
            for (int j = 0; j < 4; ++j)
                acc[i][j] += av[i] * bw[j];
    }
    int h = half * 4 + h2;
    size_t obase = (size_t)((b * NW + win) * NH + h) * (DH * DH);
    for (int i = 0; i < 4; ++i) {
        float4 o = {acc[i][0], acc[i][1], acc[i][2], acc[i][3]};
        *(float4*)&KVw[obase + (size_t)(ddq * 4 + i) * DH + dvq * 4] = o;
    }
    if (dvq == 0) {
        float4 o = {ks[0], ks[1], ks[2], ks[3]};
        *(float4*)&Ksw[(size_t)((b * NW + win) * NH + h) * DH + ddq * 4] = o;
    }
}

// ---------------------------------------------------------------------------
// K3b: coarse KV over the 256 mean tokens. One block per (b,half).
// ---------------------------------------------------------------------------
__global__ __launch_bounds__(256) void k_kvc(
        const float* __restrict__ kmf, const float* __restrict__ vm,
        float* __restrict__ KVc, float* __restrict__ Ksc) {
    int b = blockIdx.x >> 1;
    int half = blockIdx.x & 1;
    int t = threadIdx.x;
    int h2 = t >> 6;
    int q64 = t & 63;
    int ddq = q64 >> 3, dvq = q64 & 7;
    int ca = half * 128 + h2 * 32 + ddq * 4;
    int cb = half * 128 + h2 * 32 + dvq * 4;
    const float* kb = kmf + (size_t)b * NW * D;
    const float* vb = vm + (size_t)b * NW * D;
    float acc[4][4] = {};
    float ks[4] = {};
    for (int n = 0; n < NW; ++n) {
        float4 a  = *(const float4*)&kb[n * D + ca];
        float4 bv = *(const float4*)&vb[n * D + cb];
        float av[4] = {a.x, a.y, a.z, a.w};
        float bw[4] = {bv.x, bv.y, bv.z, bv.w};
        ks[0] += av[0]; ks[1] += av[1]; ks[2] += av[2]; ks[3] += av[3];
        for (int i = 0; i < 4; ++i)
            for (int j = 0; j < 4; ++j)
                acc[i][j] += av[i] * bw[j];
    }
    int h = half * 4 + h2;
    size_t obase = (size_t)(b * NH + h) * (DH * DH);
    for (int i = 0; i < 4; ++i) {
        float4 o = {acc[i][0], acc[i][1], acc[i][2], acc[i][3]};
        *(float4*)&KVc[obase + (size_t)(ddq * 4 + i) * DH + dvq * 4] = o;
    }
    if (dvq == 0) {
        float4 o = {ks[0], ks[1], ks[2], ks[3]};
        *(float4*)&Ksc[(size_t)(b * NH + h) * DH + ddq * 4] = o;
    }
}

// ---------------------------------------------------------------------------
// K4: final. One block per (b,qw,half). Sum 9 KV sources, stage Qf, compute
// msg = (Qf.KV)/(Qf.Ksum+eps), write out. qf LDS reused in-place for msg.
// ---------------------------------------------------------------------------
__global__ __launch_bounds__(256) void k_final(
        const float* __restrict__ q, const int* __restrict__ idx,
        const float* __restrict__ KVw, const float* __restrict__ Ksw,
        const float* __restrict__ KVc, const float* __restrict__ Ksc,
        float* __restrict__ out) {
    __shared__ float kv[4 * DH * DH];   // 16 KB
    __shared__ float ksl[4 * DH];       // 512 B
    __shared__ float qf[LL * 128];      // 24.5 KB (also holds msg in-place)
    __shared__ int idxl[TOPK];
    int blk = blockIdx.x;
    int b = blk >> 9;
    int qw = (blk >> 1) & 255;
    int half = blk & 1;
    int wi = qw >> 4, wj = qw & 15;
    int t = threadIdx.x;
    if (t < TOPK) idxl[t] = idx[(size_t)(b * NW + qw) * TOPK + t];
    // stage Qf = elu(q)+1 for this half's 128 channels
    for (int p = t; p < 128 * WS; p += 256) {
        int c = p / WS, r = p % WS;
        int C = half * 128 + c;
        size_t g = ((size_t)((b * D + C) * HH + wi * WS + r)) * WW + wj * WS;
        for (int x = 0; x < WS; ++x)
            qf[(r * WS + x) * 128 + c] = elu1(q[g + x]);
    }
    __syncthreads();
    // phase 1: KV = KV_coarse + sum of 8 gathered KVw ; same for Ksum
    {
        int h2 = t >> 6;
        int dd = (t & 63) >> 1;
        int dvh = t & 1;
        int h = half * 4 + h2;
        float kvacc[16] = {};
        float ksacc = 0.f;
        for (int s = 0; s <= TOPK; ++s) {
            const float* kvsrc;
            const float* kssrc;
            if (s < TOPK) {
                int srcw = idxl[s];
                kvsrc = KVw + (size_t)((b * NW + srcw) * NH + h) * (DH * DH);
                kssrc = Ksw + (size_t)((b * NW + srcw) * NH + h) * DH;
            } else {
                kvsrc = KVc + (size_t)(b * NH + h) * (DH * DH);
                kssrc = Ksc + (size_t)(b * NH + h) * DH;
            }
            const float* rowp = kvsrc + (size_t)dd * DH + dvh * 16;
            for (int j4 = 0; j4 < 4; ++j4) {
                float4 r4 = *(const float4*)&rowp[j4 * 4];
                kvacc[j4 * 4 + 0] += r4.x; kvacc[j4 * 4 + 1] += r4.y;
                kvacc[j4 * 4 + 2] += r4.z; kvacc[j4 * 4 + 3] += r4.w;
            }
            ksacc += kssrc[dd];
        }
        for (int j = 0; j < 16; ++j)
            kv[h2 * (DH * DH) + dd * DH + dvh * 16 + j] = kvacc[j];
        if (dvh == 0) ksl[h2 * DH + dd] = ksacc;
    }
    __syncthreads();
    // phase 2: msg[l][h][dv] = (Qf[l,h,:].kvcol)/(Qf[l,h,:].ks + eps)
    {
        int lset = t >> 7;          // 0: l 0..24, 1: l 25..48
        int h2 = (t >> 5) & 3;
        int dv = t & 31;
        float kvcol[DH], ksr[DH];
        for (int dd = 0; dd < DH; ++dd) {
            kvcol[dd] = kv[h2 * (DH * DH) + dd * DH + dv];
            ksr[dd]  = ksl[h2 * DH + dd];
        }
        int l0 = lset * 25;
        int l1 = l0 + 25; if (l1 > LL) l1 = LL;
        for (int l = l0; l < l1; ++l) {
            const float* qrow = &qf[l * 128 + h2 * 32];
            float m = 0.f, z = 0.f;
            for (int dd = 0; dd < DH; ++dd) {
                float qv = qrow[dd];
                m += qv * kvcol[dd];
                z += qv * ksr[dd];
            }
            // safe: the 32 lanes of this (lset,h2) group are in one wave and
            // are the only readers/writers of this qf region
            qf[l * 128 + h2 * 32 + dv] = m / (z + 1e-6f);
        }
    }
    __syncthreads();
    // write out: out[b][C][wi*7+r][wj*7+x] = msg[(r*7+x)][c]
    for (int p = t; p < 128 * WS; p += 256) {
        int c = p / WS, r = p % WS;
        int C = half * 128 + c;
        size_t g = ((size_t)((b * D + C) * HH + wi * WS + r)) * WW + wj * WS;
        for (int x = 0; x < WS; ++x)
            out[g + x] = qf[(r * WS + x) * 128 + c];
    }
}

// ---------------------------------------------------------------------------
extern "C" void kernel_launch(void* const* d_in, const int* in_sizes, int n_in,
                              void* d_out, int out_size, void* d_ws, size_t ws_size,
                              hipStream_t stream) {
    const float* q = (const float*)d_in[0];
    const float* k = (const float*)d_in[1];
    const float* v = (const float*)d_in[2];
    float* out = (float*)d_out;
    float* ws = (float*)d_ws;

    // workspace layout (floats)
    float* qm  = ws;                 // 262144
    float* kmf = ws + 262144;        // 262144
    float* vm  = ws + 524288;        // 262144
    float* kmT = ws + 786432;        // 262144
    int*   idx = (int*)(ws + 1048576);   // 8192 ints
    float* KVw = ws + 1056768;       // 8388608
    float* Ksw = ws + 9445376;       // 262144
    float* KVc = ws + 9707520;       // 32768
    float* Ksc = ws + 9740288;       // 1024
    // total: 9741312 floats = ~37.2 MB

    k_means<<<dim3(B * D), dim3(256), 0, stream>>>(q, k, v, qm, kmf, vm, kmT);
    k_topk <<<dim3(B * NW), dim3(256), 0, stream>>>(qm, kmT, idx);
    k_kvw  <<<dim3(B * NW * 2), dim3(256), 0, stream>>>(k, v, KVw, Ksw);
    k_kvc  <<<dim3(B * 2), dim3(256), 0, stream>>>(kmf, vm, KVc, Ksc);
    k_final<<<dim3(B * NW * 2), dim3(256), 0, stream>>>(q, idx, KVw, Ksw, KVc, Ksc, out);
}

// Round 2
// 390.003 us; speedup vs baseline: 1.0334x; 1.0334x over previous
//
#include <hip/hip_runtime.h>
#include <float.h>

#define B 4
#define D 256
#define HH 112
#define WW 112
#define WS 7
#define NW 256
#define LL 49
#define TOPK 8
#define NH 8
#define DH 32
#define PADR 132   // k_kvw LDS row stride (floats)
#define PADQ 136   // k_final qf row stride (bf16 elems; *2B = 272, 16B-aligned)

typedef unsigned short u16;
typedef unsigned int u32;

__device__ __forceinline__ float elu1(float x) {
    return x > 0.f ? x + 1.f : __expf(x);
}
__device__ __forceinline__ float bf2f(u16 u) {
    return __uint_as_float(((u32)u) << 16);
}
__device__ __forceinline__ u16 f2bf(float x) {
    u32 u = __float_as_uint(x);
    u32 r = (u + 0x7FFFu + ((u >> 16) & 1u)) >> 16;
    return (u16)r;
}

// ---------------------------------------------------------------------------
// K0: windowize q,k,v -> bf16 [b][win][l=49][c=256] + fp32 window means.
// Block = (b, wi, wj-half(8 windows), 32-channel group). Coalesced row reads,
// full-line window-major writes. Means accumulated fp32 via LDS atomics (the
// top-k ranking must match the fp32 reference, so means never touch bf16).
// ---------------------------------------------------------------------------
__global__ __launch_bounds__(256) void k_xform(
        const float* __restrict__ q, const float* __restrict__ k,
        const float* __restrict__ v,
        u16* __restrict__ qwin, u16* __restrict__ kwin, u16* __restrict__ vwin,
        float* __restrict__ qm, float* __restrict__ kmf,
        float* __restrict__ vm, float* __restrict__ kmT) {
    __shared__ u16 stage[32 * 392];   // 32 ch x (7 rows x 56 cols)
    __shared__ float macc[256];       // 32 ch x 8 windows
    int blk = blockIdx.x;
    int cg = blk & 7, wjh = (blk >> 3) & 1, wi = (blk >> 4) & 15, b = blk >> 8;
    int c0 = cg * 32;
    int t = threadIdx.x;
    for (int ti = 0; ti < 3; ++ti) {
        const float* src = ti == 0 ? q : (ti == 1 ? k : v);
        u16* dst = ti == 0 ? qwin : (ti == 1 ? kwin : vwin);
        macc[t] = 0.f;
        __syncthreads();
        // load fp32 rows (coalesced), stage bf16, accumulate window sums
        for (int p = t; p < 3136; p += 256) {
            int c = p / 98;
            int f = (p - c * 98) * 4;          // 0..391, mult of 4
            int r = f / 56, lcol = f - r * 56;
            int colg = wjh * 56 + lcol;
            const float* gp = src +
                ((size_t)((b * D + c0 + c) * HH + wi * WS + r)) * WW + colg;
            float4 x = *(const float4*)gp;
            u32 w0 = ((u32)f2bf(x.y) << 16) | f2bf(x.x);
            u32 w1 = ((u32)f2bf(x.w) << 16) | f2bf(x.z);
            *(u32*)&stage[c * 392 + f] = w0;
            *(u32*)&stage[c * 392 + f + 2] = w1;
            int wj0 = colg / 7;
            int n0 = (wj0 + 1) * 7 - colg; if (n0 > 4) n0 = 4;
            float xs[4] = {x.x, x.y, x.z, x.w};
            float s0 = 0.f, s1 = 0.f;
            for (int j = 0; j < 4; ++j) { if (j < n0) s0 += xs[j]; else s1 += xs[j]; }
            atomicAdd(&macc[c * 8 + (wj0 - wjh * 8)], s0);
            if (n0 < 4) atomicAdd(&macc[c * 8 + (wj0 + 1 - wjh * 8)], s1);
        }
        __syncthreads();
        // means out: 256 (c, wj) pairs
        {
            int c = t >> 3, wjl = t & 7;
            int C = c0 + c;
            int win = wi * 16 + wjh * 8 + wjl;
            float mean = macc[c * 8 + wjl] * (1.f / 49.f);
            if (ti == 0) qm[(size_t)(b * NW + win) * D + C] = mean;
            else if (ti == 1) {
                kmf[(size_t)(b * NW + win) * D + C] = elu1(mean);
                kmT[(size_t)(b * D + C) * NW + win] = mean;
            } else vm[(size_t)(b * NW + win) * D + C] = mean;
        }
        // window-major write: 16-B chunks, fully coalesced & line-aligned
        for (int p = t; p < 1568; p += 256) {
            int wjl = p / 196;
            int rem = p - wjl * 196;
            int l = rem >> 2, oct = rem & 3;
            int r = l / 7, x = l - r * 7;
            int lcol = wjl * 7 + x;
            u32 wds[4];
            for (int h = 0; h < 4; ++h) {
                int cA = oct * 8 + h * 2;
                u16 a  = stage[cA * 392 + r * 56 + lcol];
                u16 bq = stage[(cA + 1) * 392 + r * 56 + lcol];
                wds[h] = ((u32)bq << 16) | a;
            }
            int win = wi * 16 + wjh * 8 + wjl;
            u16* gp = dst + ((size_t)(b * NW + win) * LL + l) * D + c0 + oct * 8;
            *(uint4*)gp = make_uint4(wds[0], wds[1], wds[2], wds[3]);
        }
        __syncthreads();
    }
}

// ---------------------------------------------------------------------------
// K2: sim row + top-8 via wave shuffle argmax (tie -> smaller index).
// ---------------------------------------------------------------------------
__global__ __launch_bounds__(256) void k_topk(
        const float* __restrict__ qm, const float* __restrict__ kmT,
        int* __restrict__ idx) {
    __shared__ float qrow[D];
    __shared__ float cval[4];
    __shared__ int cidx[4];
    __shared__ int winner;
    int b = blockIdx.x >> 8;
    int qw = blockIdx.x & 255;
    int t = threadIdx.x;
    qrow[t] = qm[(size_t)(b * NW + qw) * D + t];
    __syncthreads();
    const float* kb = kmT + (size_t)b * D * NW + t;
    float a0 = 0.f, a1 = 0.f, a2 = 0.f, a3 = 0.f;
    for (int d = 0; d < D; d += 4) {
        a0 += qrow[d]     * kb[(size_t)d * NW];
        a1 += qrow[d + 1] * kb[(size_t)(d + 1) * NW];
        a2 += qrow[d + 2] * kb[(size_t)(d + 2) * NW];
        a3 += qrow[d + 3] * kb[(size_t)(d + 3) * NW];
    }
    float val = (a0 + a1) + (a2 + a3);
    for (int sel = 0; sel < TOPK; ++sel) {
        float v = val; int ii = t;
        for (int off = 32; off > 0; off >>= 1) {
            float ov = __shfl_xor(v, off);
            int oi = __shfl_xor(ii, off);
            if (ov > v || (ov == v && oi < ii)) { v = ov; ii = oi; }
        }
        if ((t & 63) == 0) { cval[t >> 6] = v; cidx[t >> 6] = ii; }
        __syncthreads();
        if (t == 0) {
            float bv = cval[0]; int bi = cidx[0];
            for (int w = 1; w < 4; ++w)
                if (cval[w] > bv || (cval[w] == bv && cidx[w] < bi)) {
                    bv = cval[w]; bi = cidx[w];
                }
            idx[(size_t)(b * NW + qw) * TOPK + sel] = bi;
            winner = bi;
        }
        __syncthreads();
        if (t == winner) val = -FLT_MAX;
    }
}

// ---------------------------------------------------------------------------
// K3: per-(b,win,half) KVw[h][32][32] + Ksw. Contiguous bf16 window reads.
// ---------------------------------------------------------------------------
__global__ __launch_bounds__(256) void k_kvw(
        const u16* __restrict__ kwin, const u16* __restrict__ vwin,
        float* __restrict__ KVw, float* __restrict__ Ksw) {
    __shared__ float kf[LL * PADR];
    __shared__ float vf[LL * PADR];
    int blk = blockIdx.x;
    int b = blk >> 9;
    int win = (blk >> 1) & 255;
    int half = blk & 1;
    int t = threadIdx.x;
    for (int ti = 0; ti < 2; ++ti) {
        const u16* src = ti ? vwin : kwin;
        float* dstl = ti ? vf : kf;
        for (int p = t; p < 784; p += 256) {
            int l = p >> 4, oct = p & 15;
            const u16* gp = src +
                ((size_t)(b * NW + win) * LL + l) * D + half * 128 + oct * 8;
            uint4 raw = *(const uint4*)gp;
            u32 wsv[4] = {raw.x, raw.y, raw.z, raw.w};
            float vals[8];
            for (int h = 0; h < 4; ++h) {
                vals[2 * h]     = __uint_as_float(wsv[h] << 16);
                vals[2 * h + 1] = __uint_as_float(wsv[h] & 0xffff0000u);
            }
            if (ti == 0) for (int j = 0; j < 8; ++j) vals[j] = elu1(vals[j]);
            float4 v0 = {vals[0], vals[1], vals[2], vals[3]};
            float4 v1 = {vals[4], vals[5], vals[6], vals[7]};
            *(float4*)&dstl[l * PADR + oct * 8] = v0;
            *(float4*)&dstl[l * PADR + oct * 8 + 4] = v1;
        }
    }
    __syncthreads();
    int h2 = t >> 6;
    int q64 = t & 63;
    int ddq = q64 >> 3, dvq = q64 & 7;
    int ab = h2 * 32 + ddq * 4;
    int bb = h2 * 32 + dvq * 4;
    float acc[4][4] = {};
    float ks[4] = {};
    for (int l = 0; l < LL; ++l) {
        float4 a  = *(const float4*)&kf[l * PADR + ab];
        float4 bv = *(const float4*)&vf[l * PADR + bb];
        float av[4] = {a.x, a.y, a.z, a.w};
        float bw[4] = {bv.x, bv.y, bv.z, bv.w};
        ks[0] += av[0]; ks[1] += av[1]; ks[2] += av[2]; ks[3] += av[3];
        for (int i = 0; i < 4; ++i)
            for (int j = 0; j < 4; ++j)
                acc[i][j] += av[i] * bw[j];
    }
    int h = half * 4 + h2;
    size_t obase = (size_t)((b * NW + win) * NH + h) * (DH * DH);
    for (int i = 0; i < 4; ++i) {
        float4 o = {acc[i][0], acc[i][1], acc[i][2], acc[i][3]};
        *(float4*)&KVw[obase + (size_t)(ddq * 4 + i) * DH + dvq * 4] = o;
    }
    if (dvq == 0) {
        float4 o = {ks[0], ks[1], ks[2], ks[3]};
        *(float4*)&Ksw[(size_t)((b * NW + win) * NH + h) * DH + ddq * 4] = o;
    }
}

// ---------------------------------------------------------------------------
// K3b: coarse KV over 256 mean tokens.
// ---------------------------------------------------------------------------
__global__ __launch_bounds__(256) void k_kvc(
        const float* __restrict__ kmf, const float* __restrict__ vm,
        float* __restrict__ KVc, float* __restrict__ Ksc) {
    int b = blockIdx.x >> 1;
    int half = blockIdx.x & 1;
    int t = threadIdx.x;
    int h2 = t >> 6;
    int q64 = t & 63;
    int ddq = q64 >> 3, dvq = q64 & 7;
    int ca = half * 128 + h2 * 32 + ddq * 4;
    int cb = half * 128 + h2 * 32 + dvq * 4;
    const float* kb = kmf + (size_t)b * NW * D;
    const float* vb = vm + (size_t)b * NW * D;
    float acc[4][4] = {};
    float ks[4] = {};
#pragma unroll 4
    for (int n = 0; n < NW; ++n) {
        float4 a  = *(const float4*)&kb[n * D + ca];
        float4 bv = *(const float4*)&vb[n * D + cb];
        float av[4] = {a.x, a.y, a.z, a.w};
        float bw[4] = {bv.x, bv.y, bv.z, bv.w};
        ks[0] += av[0]; ks[1] += av[1]; ks[2] += av[2]; ks[3] += av[3];
        for (int i = 0; i < 4; ++i)
            for (int j = 0; j < 4; ++j)
                acc[i][j] += av[i] * bw[j];
    }
    int h = half * 4 + h2;
    size_t obase = (size_t)(b * NH + h) * (DH * DH);
    for (int i = 0; i < 4; ++i) {
        float4 o = {acc[i][0], acc[i][1], acc[i][2], acc[i][3]};
        *(float4*)&KVc[obase + (size_t)(ddq * 4 + i) * DH + dvq * 4] = o;
    }
    if (dvq == 0) {
        float4 o = {ks[0], ks[1], ks[2], ks[3]};
        *(float4*)&Ksc[(size_t)(b * NH + h) * DH + ddq * 4] = o;
    }
}

// ---------------------------------------------------------------------------
// K4: gather-sum KV, apply Qf, write msg (bf16, window-major, aliases qwin).
// XCD-swizzled block order for gather L2 locality.
// ---------------------------------------------------------------------------
__global__ __launch_bounds__(256) void k_final(
        const u16* qwin, const int* __restrict__ idx,
        const float* __restrict__ KVw, const float* __restrict__ Ksw,
        const float* __restrict__ KVc, const float* __restrict__ Ksc,
        u16* msg) {
    __shared__ float kv[4 * DH * DH];   // 16 KB
    __shared__ float ksl[4 * DH];
    __shared__ u16 qf[LL * PADQ];       // 13.0 KB (Qf bf16; msg in-place)
    __shared__ int idxl[TOPK];
    int blk = blockIdx.x;
    int lin = ((blk & 7) << 8) | (blk >> 3);   // XCD swizzle: 8 window-rows/XCD
    int half = lin & 1;
    int qw = (lin >> 1) & 255;
    int b = lin >> 9;
    int t = threadIdx.x;
    if (t < TOPK) idxl[t] = idx[(size_t)(b * NW + qw) * TOPK + t];
    // stage Qf = elu(q)+1 as bf16
    for (int p = t; p < 784; p += 256) {
        int l = p >> 4, oct = p & 15;
        const u16* gp = qwin +
            ((size_t)(b * NW + qw) * LL + l) * D + half * 128 + oct * 8;
        uint4 raw = *(const uint4*)gp;
        u32 wsin[4] = {raw.x, raw.y, raw.z, raw.w};
        u32 wout[4];
        for (int h = 0; h < 4; ++h) {
            float lo = elu1(__uint_as_float(wsin[h] << 16));
            float hi = elu1(__uint_as_float(wsin[h] & 0xffff0000u));
            wout[h] = ((u32)f2bf(hi) << 16) | f2bf(lo);
        }
        *(uint4*)&qf[l * PADQ + oct * 8] = make_uint4(wout[0], wout[1], wout[2], wout[3]);
    }
    __syncthreads();
    // phase 1: KV = KV_coarse + sum of 8 gathered KVw ; same for Ksum
    {
        int h2 = t >> 6;
        int dd = (t & 63) >> 1;
        int dvh = t & 1;
        int h = half * 4 + h2;
        float kvacc[16] = {};
        float ksacc = 0.f;
        for (int s = 0; s <= TOPK; ++s) {
            const float* kvsrc;
            const float* kssrc;
            if (s < TOPK) {
                int srcw = idxl[s];
                kvsrc = KVw + (size_t)((b * NW + srcw) * NH + h) * (DH * DH);
                kssrc = Ksw + (size_t)((b * NW + srcw) * NH + h) * DH;
            } else {
                kvsrc = KVc + (size_t)(b * NH + h) * (DH * DH);
                kssrc = Ksc + (size_t)(b * NH + h) * DH;
            }
            const float* rowp = kvsrc + (size_t)dd * DH + dvh * 16;
            for (int j4 = 0; j4 < 4; ++j4) {
                float4 r4 = *(const float4*)&rowp[j4 * 4];
                kvacc[j4 * 4 + 0] += r4.x; kvacc[j4 * 4 + 1] += r4.y;
                kvacc[j4 * 4 + 2] += r4.z; kvacc[j4 * 4 + 3] += r4.w;
            }
            ksacc += kssrc[dd];
        }
        for (int j = 0; j < 16; ++j)
            kv[h2 * (DH * DH) + dd * DH + dvh * 16 + j] = kvacc[j];
        if (dvh == 0) ksl[h2 * DH + dd] = ksacc;
    }
    __syncthreads();
    // phase 2: msg[l][h][dv] = (Qf.kvcol)/(Qf.ks + eps), in-place into qf
    {
        int lset = t >> 7;
        int h2 = (t >> 5) & 3;
        int dv = t & 31;
        float kvcol[DH], ksr[DH];
        for (int dd = 0; dd < DH; ++dd) {
            kvcol[dd] = kv[h2 * (DH * DH) + dd * DH + dv];
            ksr[dd]  = ksl[h2 * DH + dd];
        }
        int l0 = lset * 25;
        int l1 = l0 + 25; if (l1 > LL) l1 = LL;
        for (int l = l0; l < l1; ++l) {
            const u16* qrow = &qf[l * PADQ + h2 * DH];
            float m = 0.f, z = 0.f;
            for (int dd2 = 0; dd2 < 16; ++dd2) {
                u32 w = *(const u32*)&qrow[dd2 * 2];
                float q0 = __uint_as_float(w << 16);
                float q1 = __uint_as_float(w & 0xffff0000u);
                m += q0 * kvcol[2 * dd2] + q1 * kvcol[2 * dd2 + 1];
                z += q0 * ksr[2 * dd2] + q1 * ksr[2 * dd2 + 1];
            }
            qf[l * PADQ + h2 * DH + dv] = f2bf(m / (z + 1e-6f));
        }
    }
    __syncthreads();
    // phase 3: copy msg tile out (fully coalesced, aliases this block's qwin)
    for (int p = t; p < 784; p += 256) {
        int l = p >> 4, oct = p & 15;
        uint4 w = *(const uint4*)&qf[l * PADQ + oct * 8];
        u16* gp = msg + ((size_t)(b * NW + qw) * LL + l) * D + half * 128 + oct * 8;
        *(uint4*)gp = w;
    }
}

// ---------------------------------------------------------------------------
// K5: window-major msg -> image layout, full-line coalesced writes.
// ---------------------------------------------------------------------------
__global__ __launch_bounds__(256) void k_out(
        const u16* __restrict__ msg, float* __restrict__ out) {
    __shared__ u16 ms[16 * LL * 32];   // 50176 B
    int blk = blockIdx.x;
    int cg = blk & 7, wi = (blk >> 3) & 15, b = blk >> 7;
    int c0 = cg * 32;
    int t = threadIdx.x;
    for (int p = t; p < 3136; p += 256) {
        int wj = p / 196;
        int rem = p - wj * 196;
        int l = rem >> 2, oct = rem & 3;
        const u16* gp = msg +
            ((size_t)(b * NW + wi * 16 + wj) * LL + l) * D + c0 + oct * 8;
        uint4 raw = *(const uint4*)gp;
        *(uint4*)&ms[(wj * LL + l) * 32 + oct * 8] = raw;
    }
    __syncthreads();
    for (int p = t; p < 6272; p += 256) {
        int c = p / 196;
        int rem = p - c * 196;
        int f = rem * 4;
        int r = f / 112, col = f - r * 112;
        float4 o;
        float* op = (float*)&o;
        for (int j = 0; j < 4; ++j) {
            int xg = col + j;
            int wj = xg / 7, x = xg - wj * 7;
            int l = r * 7 + x;
            op[j] = bf2f(ms[(wj * LL + l) * 32 + c]);
        }
        float* gp = out + ((size_t)((b * D + c0 + c) * HH + wi * WS + r)) * WW + col;
        *(float4*)gp = o;
    }
}

// ---------------------------------------------------------------------------
extern "C" void kernel_launch(void* const* d_in, const int* in_sizes, int n_in,
                              void* d_out, int out_size, void* d_ws, size_t ws_size,
                              hipStream_t stream) {
    const float* q = (const float*)d_in[0];
    const float* k = (const float*)d_in[1];
    const float* v = (const float*)d_in[2];
    float* out = (float*)d_out;
    char* base = (char*)d_ws;

    // byte offsets (MiB-granular headroom)
    float* qm  = (float*)(base);                                  // 1 MiB
    float* kmf = (float*)(base + (size_t)1 * (1 << 20));          // 1 MiB
    float* vm  = (float*)(base + (size_t)2 * (1 << 20));          // 1 MiB
    float* kmT = (float*)(base + (size_t)3 * (1 << 20));          // 1 MiB
    int*   idx = (int*)  (base + (size_t)4 * (1 << 20));          // 32 KiB
    float* Ksw = (float*)(base + (size_t)4 * (1 << 20) + (1 << 15));        // 1 MiB
    float* KVc = (float*)(base + (size_t)5 * (1 << 20) + (1 << 15));        // 128 KiB
    float* Ksc = (float*)(base + (size_t)5 * (1 << 20) + (1 << 15) + (1 << 17)); // 4 KiB
    float* KVw = (float*)(base + (size_t)6 * (1 << 20));          // 32 MiB
    u16* kwin  = (u16*)(base + (size_t)40 * (1 << 20));           // 24.5 MiB
    u16* vwin  = (u16*)(base + (size_t)65 * (1 << 20));           // 24.5 MiB
    u16* qwin  = (u16*)(base + (size_t)90 * (1 << 20));           // 24.5 MiB (msg alias)
    // total required: ~114.5 MiB

    k_xform<<<dim3(B * 16 * 2 * 8), dim3(256), 0, stream>>>(
        q, k, v, qwin, kwin, vwin, qm, kmf, vm, kmT);
    k_topk <<<dim3(B * NW), dim3(256), 0, stream>>>(qm, kmT, idx);
    k_kvw  <<<dim3(B * NW * 2), dim3(256), 0, stream>>>(kwin, vwin, KVw, Ksw);
    k_kvc  <<<dim3(B * 2), dim3(256), 0, stream>>>(kmf, vm, KVc, Ksc);
    k_final<<<dim3(B * NW * 2), dim3(256), 0, stream>>>(
        qwin, idx, KVw, Ksw, KVc, Ksc, qwin /* msg aliases qwin, disjoint per block */);
    k_out  <<<dim3(B * 16 * 8), dim3(256), 0, stream>>>(qwin, out);
}

// Round 3
// 381.534 us; speedup vs baseline: 1.0563x; 1.0222x over previous
//
#include <hip/hip_runtime.h>
#include <float.h>

#define B 4
#define D 256
#define HH 112
#define WW 112
#define WS 7
#define NW 256
#define LL 49
#define TOPK 8
#define NH 8
#define DH 32
#define PADK 136   // k_kvw LDS row stride (bf16 elems; *2B = 272 = 17*16, b128-aligned)
#define PADQ 136   // k_final qf row stride (bf16 elems)

typedef unsigned short u16;
typedef unsigned int u32;

__device__ __forceinline__ float elu1(float x) {
    return x > 0.f ? x + 1.f : __expf(x);
}
__device__ __forceinline__ float bf2f(u16 u) {
    return __uint_as_float(((u32)u) << 16);
}
__device__ __forceinline__ u16 f2bf(float x) {
    u32 u = __float_as_uint(x);
    u32 r = (u + 0x7FFFu + ((u >> 16) & 1u)) >> 16;
    return (u16)r;
}

// ---------------------------------------------------------------------------
// K0: windowize one tensor -> bf16 [b][win][l=49][c=256] + fp32 window means.
// Block = (ti, b, wi, wjh, 16-ch group). fp32 LDS stage; means by ownership
// (no atomics); bf16 conversion only at the window-major write.
// ---------------------------------------------------------------------------
__global__ __launch_bounds__(256) void k_xform(
        const float* __restrict__ q, const float* __restrict__ k,
        const float* __restrict__ v,
        u16* __restrict__ qwin, u16* __restrict__ kwin, u16* __restrict__ vwin,
        float* __restrict__ qm, float* __restrict__ kmf,
        float* __restrict__ vm, float* __restrict__ kmT) {
    __shared__ float stage[16 * 392];   // 16 ch x (7 rows x 56 cols) = 25088 B
    int blk = blockIdx.x;
    int cg = blk & 15, wjh = (blk >> 4) & 1, wi = (blk >> 5) & 15;
    int b = (blk >> 9) & 3, ti = blk >> 11;
    int c0 = cg * 16;
    int t = threadIdx.x;
    const float* src = ti == 0 ? q : (ti == 1 ? k : v);
    u16* dst = ti == 0 ? qwin : (ti == 1 ? kwin : vwin);

    // phase A: coalesced fp32 row loads -> LDS
    for (int p = t; p < 1568; p += 256) {
        int c = p / 98;
        int f4 = (p - c * 98) * 4;      // 0..388, mult of 4
        int r = f4 / 56, lcol = f4 - r * 56;
        const float* gp = src +
            ((size_t)((b * D + c0 + c) * HH + wi * WS + r)) * WW + wjh * 56 + lcol;
        *(float4*)&stage[c * 392 + f4] = *(const float4*)gp;
    }
    __syncthreads();

    // phase B: fp32 means, thread (c,wj) owns its window (no atomics)
    if (t < 128) {
        int c = t >> 3, wjl = t & 7;
        int base = c * 392 + wjl * 7;
        float s = 0.f;
        for (int r = 0; r < WS; ++r)
            for (int x = 0; x < WS; ++x)
                s += stage[base + r * 56 + x];
        float mean = s * (1.f / 49.f);
        int C = c0 + c;
        int win = wi * 16 + wjh * 8 + wjl;
        if (ti == 0) qm[(size_t)(b * NW + win) * D + C] = mean;
        else if (ti == 1) {
            kmf[(size_t)(b * NW + win) * D + C] = elu1(mean);
            kmT[(size_t)(b * D + C) * NW + win] = mean;
        } else vm[(size_t)(b * NW + win) * D + C] = mean;
    }
    __syncthreads();

    // phase C: bf16 window-major write, 16-B chunks (64-B line granular)
    for (int p = t; p < 784; p += 256) {
        int wjl = p / 98;
        int rem = p - wjl * 98;
        int l = rem >> 1, oct = rem & 1;
        int r = l / 7, x = l - r * 7;
        int fo = r * 56 + wjl * 7 + x;
        u32 wds[4];
        for (int h = 0; h < 4; ++h) {
            int cA = oct * 8 + h * 2;
            u16 a  = f2bf(stage[cA * 392 + fo]);
            u16 bq = f2bf(stage[(cA + 1) * 392 + fo]);
            wds[h] = ((u32)bq << 16) | a;
        }
        int win = wi * 16 + wjh * 8 + wjl;
        u16* gp = dst + ((size_t)(b * NW + win) * LL + l) * D + c0 + oct * 8;
        *(uint4*)gp = make_uint4(wds[0], wds[1], wds[2], wds[3]);
    }
}

// ---------------------------------------------------------------------------
// K2: sim row + top-8 via wave shuffle argmax (tie -> smaller index).
// ---------------------------------------------------------------------------
__global__ __launch_bounds__(256) void k_topk(
        const float* __restrict__ qm, const float* __restrict__ kmT,
        int* __restrict__ idx) {
    __shared__ float qrow[D];
    __shared__ float cval[4];
    __shared__ int cidx[4];
    __shared__ int winner;
    int b = blockIdx.x >> 8;
    int qw = blockIdx.x & 255;
    int t = threadIdx.x;
    qrow[t] = qm[(size_t)(b * NW + qw) * D + t];
    __syncthreads();
    const float* kb = kmT + (size_t)b * D * NW + t;
    float a0 = 0.f, a1 = 0.f, a2 = 0.f, a3 = 0.f;
    for (int d = 0; d < D; d += 4) {
        a0 += qrow[d]     * kb[(size_t)d * NW];
        a1 += qrow[d + 1] * kb[(size_t)(d + 1) * NW];
        a2 += qrow[d + 2] * kb[(size_t)(d + 2) * NW];
        a3 += qrow[d + 3] * kb[(size_t)(d + 3) * NW];
    }
    float val = (a0 + a1) + (a2 + a3);
    for (int sel = 0; sel < TOPK; ++sel) {
        float v = val; int ii = t;
        for (int off = 32; off > 0; off >>= 1) {
            float ov = __shfl_xor(v, off);
            int oi = __shfl_xor(ii, off);
            if (ov > v || (ov == v && oi < ii)) { v = ov; ii = oi; }
        }
        if ((t & 63) == 0) { cval[t >> 6] = v; cidx[t >> 6] = ii; }
        __syncthreads();
        if (t == 0) {
            float bv = cval[0]; int bi = cidx[0];
            for (int w = 1; w < 4; ++w)
                if (cval[w] > bv || (cval[w] == bv && cidx[w] < bi)) {
                    bv = cval[w]; bi = cidx[w];
                }
            idx[(size_t)(b * NW + qw) * TOPK + sel] = bi;
            winner = bi;
        }
        __syncthreads();
        if (t == winner) val = -FLT_MAX;
    }
}

// ---------------------------------------------------------------------------
// K3: per-(b,win,half) KVw[h][32][32] + Ksw. bf16 LDS stage (27 KB -> 5/CU).
// ---------------------------------------------------------------------------
__global__ __launch_bounds__(256) void k_kvw(
        const u16* __restrict__ kwin, const u16* __restrict__ vwin,
        float* __restrict__ KVw, float* __restrict__ Ksw) {
    __shared__ u16 kf[LL * PADK];
    __shared__ u16 vf[LL * PADK];
    int blk = blockIdx.x;
    int b = blk >> 9;
    int win = (blk >> 1) & 255;
    int half = blk & 1;
    int t = threadIdx.x;
    // stage: K gets elu applied (bf16->f32->elu->bf16), V is a raw copy
    for (int p = t; p < 784; p += 256) {
        int l = p >> 4, oct = p & 15;
        size_t goff = ((size_t)(b * NW + win) * LL + l) * D + half * 128 + oct * 8;
        uint4 raw = *(const uint4*)(kwin + goff);
        u32 w[4] = {raw.x, raw.y, raw.z, raw.w};
        u32 o[4];
        for (int h = 0; h < 4; ++h) {
            float lo = elu1(__uint_as_float(w[h] << 16));
            float hi = elu1(__uint_as_float(w[h] & 0xffff0000u));
            o[h] = ((u32)f2bf(hi) << 16) | f2bf(lo);
        }
        *(uint4*)&kf[l * PADK + oct * 8] = make_uint4(o[0], o[1], o[2], o[3]);
        *(uint4*)&vf[l * PADK + oct * 8] = *(const uint4*)(vwin + goff);
    }
    __syncthreads();
    int h2 = t >> 6;
    int q64 = t & 63;
    int ddq = q64 >> 3, dvq = q64 & 7;
    int ab = h2 * 32 + ddq * 4;
    int bb = h2 * 32 + dvq * 4;
    float acc[4][4] = {};
    float ks[4] = {};
    for (int l = 0; l < LL; ++l) {
        uint2 kr = *(const uint2*)&kf[l * PADK + ab];
        uint2 vr = *(const uint2*)&vf[l * PADK + bb];
        float av[4] = {
            __uint_as_float(kr.x << 16), __uint_as_float(kr.x & 0xffff0000u),
            __uint_as_float(kr.y << 16), __uint_as_float(kr.y & 0xffff0000u)};
        float bw[4] = {
            __uint_as_float(vr.x << 16), __uint_as_float(vr.x & 0xffff0000u),
            __uint_as_float(vr.y << 16), __uint_as_float(vr.y & 0xffff0000u)};
        ks[0] += av[0]; ks[1] += av[1]; ks[2] += av[2]; ks[3] += av[3];
        for (int i = 0; i < 4; ++i)
            for (int j = 0; j < 4; ++j)
                acc[i][j] += av[i] * bw[j];
    }
    int h = half * 4 + h2;
    size_t obase = (size_t)((b * NW + win) * NH + h) * (DH * DH);
    for (int i = 0; i < 4; ++i) {
        float4 o = {acc[i][0], acc[i][1], acc[i][2], acc[i][3]};
        *(float4*)&KVw[obase + (size_t)(ddq * 4 + i) * DH + dvq * 4] = o;
    }
    if (dvq == 0) {
        float4 o = {ks[0], ks[1], ks[2], ks[3]};
        *(float4*)&Ksw[(size_t)((b * NW + win) * NH + h) * DH + ddq * 4] = o;
    }
}

// ---------------------------------------------------------------------------
// K3b: coarse KV over 256 mean tokens.
// ---------------------------------------------------------------------------
__global__ __launch_bounds__(256) void k_kvc(
        const float* __restrict__ kmf, const float* __restrict__ vm,
        float* __restrict__ KVc, float* __restrict__ Ksc) {
    int b = blockIdx.x >> 1;
    int half = blockIdx.x & 1;
    int t = threadIdx.x;
    int h2 = t >> 6;
    int q64 = t & 63;
    int ddq = q64 >> 3, dvq = q64 & 7;
    int ca = half * 128 + h2 * 32 + ddq * 4;
    int cb = half * 128 + h2 * 32 + dvq * 4;
    const float* kb = kmf + (size_t)b * NW * D;
    const float* vb = vm + (size_t)b * NW * D;
    float acc[4][4] = {};
    float ks[4] = {};
#pragma unroll 4
    for (int n = 0; n < NW; ++n) {
        float4 a  = *(const float4*)&kb[n * D + ca];
        float4 bv = *(const float4*)&vb[n * D + cb];
        float av[4] = {a.x, a.y, a.z, a.w};
        float bw[4] = {bv.x, bv.y, bv.z, bv.w};
        ks[0] += av[0]; ks[1] += av[1]; ks[2] += av[2]; ks[3] += av[3];
        for (int i = 0; i < 4; ++i)
            for (int j = 0; j < 4; ++j)
                acc[i][j] += av[i] * bw[j];
    }
    int h = half * 4 + h2;
    size_t obase = (size_t)(b * NH + h) * (DH * DH);
    for (int i = 0; i < 4; ++i) {
        float4 o = {acc[i][0], acc[i][1], acc[i][2], acc[i][3]};
        *(float4*)&KVc[obase + (size_t)(ddq * 4 + i) * DH + dvq * 4] = o;
    }
    if (dvq == 0) {
        float4 o = {ks[0], ks[1], ks[2], ks[3]};
        *(float4*)&Ksc[(size_t)(b * NH + h) * DH + ddq * 4] = o;
    }
}

// ---------------------------------------------------------------------------
// K4: gather-sum KV, apply Qf, write msg (bf16, window-major, aliases qwin).
// XCD-swizzled block order for gather L2 locality.
// ---------------------------------------------------------------------------
__global__ __launch_bounds__(256) void k_final(
        const u16* qwin, const int* __restrict__ idx,
        const float* __restrict__ KVw, const float* __restrict__ Ksw,
        const float* __restrict__ KVc, const float* __restrict__ Ksc,
        u16* msg) {
    __shared__ float kv[4 * DH * DH];   // 16 KB
    __shared__ float ksl[4 * DH];
    __shared__ u16 qf[LL * PADQ];       // 13.0 KB (Qf bf16; msg in-place)
    __shared__ int idxl[TOPK];
    int blk = blockIdx.x;
    int lin = ((blk & 7) << 8) | (blk >> 3);   // XCD swizzle
    int half = lin & 1;
    int qw = (lin >> 1) & 255;
    int b = lin >> 9;
    int t = threadIdx.x;
    if (t < TOPK) idxl[t] = idx[(size_t)(b * NW + qw) * TOPK + t];
    for (int p = t; p < 784; p += 256) {
        int l = p >> 4, oct = p & 15;
        const u16* gp = qwin +
            ((size_t)(b * NW + qw) * LL + l) * D + half * 128 + oct * 8;
        uint4 raw = *(const uint4*)gp;
        u32 wsin[4] = {raw.x, raw.y, raw.z, raw.w};
        u32 wout[4];
        for (int h = 0; h < 4; ++h) {
            float lo = elu1(__uint_as_float(wsin[h] << 16));
            float hi = elu1(__uint_as_float(wsin[h] & 0xffff0000u));
            wout[h] = ((u32)f2bf(hi) << 16) | f2bf(lo);
        }
        *(uint4*)&qf[l * PADQ + oct * 8] = make_uint4(wout[0], wout[1], wout[2], wout[3]);
    }
    __syncthreads();
    {
        int h2 = t >> 6;
        int dd = (t & 63) >> 1;
        int dvh = t & 1;
        int h = half * 4 + h2;
        float kvacc[16] = {};
        float ksacc = 0.f;
        for (int s = 0; s <= TOPK; ++s) {
            const float* kvsrc;
            const float* kssrc;
            if (s < TOPK) {
                int srcw = idxl[s];
                kvsrc = KVw + (size_t)((b * NW + srcw) * NH + h) * (DH * DH);
                kssrc = Ksw + (size_t)((b * NW + srcw) * NH + h) * DH;
            } else {
                kvsrc = KVc + (size_t)(b * NH + h) * (DH * DH);
                kssrc = Ksc + (size_t)(b * NH + h) * DH;
            }
            const float* rowp = kvsrc + (size_t)dd * DH + dvh * 16;
            for (int j4 = 0; j4 < 4; ++j4) {
                float4 r4 = *(const float4*)&rowp[j4 * 4];
                kvacc[j4 * 4 + 0] += r4.x; kvacc[j4 * 4 + 1] += r4.y;
                kvacc[j4 * 4 + 2] += r4.z; kvacc[j4 * 4 + 3] += r4.w;
            }
            ksacc += kssrc[dd];
        }
        for (int j = 0; j < 16; ++j)
            kv[h2 * (DH * DH) + dd * DH + dvh * 16 + j] = kvacc[j];
        if (dvh == 0) ksl[h2 * DH + dd] = ksacc;
    }
    __syncthreads();
    {
        int lset = t >> 7;
        int h2 = (t >> 5) & 3;
        int dv = t & 31;
        float kvcol[DH], ksr[DH];
        for (int dd = 0; dd < DH; ++dd) {
            kvcol[dd] = kv[h2 * (DH * DH) + dd * DH + dv];
            ksr[dd]  = ksl[h2 * DH + dd];
        }
        int l0 = lset * 25;
        int l1 = l0 + 25; if (l1 > LL) l1 = LL;
        for (int l = l0; l < l1; ++l) {
            const u16* qrow = &qf[l * PADQ + h2 * DH];
            float m = 0.f, z = 0.f;
            for (int dd2 = 0; dd2 < 16; ++dd2) {
                u32 w = *(const u32*)&qrow[dd2 * 2];
                float q0 = __uint_as_float(w << 16);
                float q1 = __uint_as_float(w & 0xffff0000u);
                m += q0 * kvcol[2 * dd2] + q1 * kvcol[2 * dd2 + 1];
                z += q0 * ksr[2 * dd2] + q1 * ksr[2 * dd2 + 1];
            }
            qf[l * PADQ + h2 * DH + dv] = f2bf(m / (z + 1e-6f));
        }
    }
    __syncthreads();
    for (int p = t; p < 784; p += 256) {
        int l = p >> 4, oct = p & 15;
        uint4 w = *(const uint4*)&qf[l * PADQ + oct * 8];
        u16* gp = msg + ((size_t)(b * NW + qw) * LL + l) * D + half * 128 + oct * 8;
        *(uint4*)gp = w;
    }
}

// ---------------------------------------------------------------------------
// K5: window-major msg -> image layout, full-line coalesced writes.
// ---------------------------------------------------------------------------
__global__ __launch_bounds__(256) void k_out(
        const u16* __restrict__ msg, float* __restrict__ out) {
    __shared__ u16 ms[16 * LL * 32];   // 50176 B
    int blk = blockIdx.x;
    int cg = blk & 7, wi = (blk >> 3) & 15, b = blk >> 7;
    int c0 = cg * 32;
    int t = threadIdx.x;
    for (int p = t; p < 3136; p += 256) {
        int wj = p / 196;
        int rem = p - wj * 196;
        int l = rem >> 2, oct = rem & 3;
        const u16* gp = msg +
            ((size_t)(b * NW + wi * 16 + wj) * LL + l) * D + c0 + oct * 8;
        uint4 raw = *(const uint4*)gp;
        *(uint4*)&ms[(wj * LL + l) * 32 + oct * 8] = raw;
    }
    __syncthreads();
    for (int p = t; p < 6272; p += 256) {
        int c = p / 196;
        int rem = p - c * 196;
        int f = rem * 4;
        int r = f / 112, col = f - r * 112;
        float4 o;
        float* op = (float*)&o;
        for (int j = 0; j < 4; ++j) {
            int xg = col + j;
            int wj = xg / 7, x = xg - wj * 7;
            int l = r * 7 + x;
            op[j] = bf2f(ms[(wj * LL + l) * 32 + c]);
        }
        float* gp = out + ((size_t)((b * D + c0 + c) * HH + wi * WS + r)) * WW + col;
        *(float4*)gp = o;
    }
}

// ---------------------------------------------------------------------------
extern "C" void kernel_launch(void* const* d_in, const int* in_sizes, int n_in,
                              void* d_out, int out_size, void* d_ws, size_t ws_size,
                              hipStream_t stream) {
    const float* q = (const float*)d_in[0];
    const float* k = (const float*)d_in[1];
    const float* v = (const float*)d_in[2];
    float* out = (float*)d_out;
    char* base = (char*)d_ws;

    float* qm  = (float*)(base);                                  // 1 MiB
    float* kmf = (float*)(base + (size_t)1 * (1 << 20));          // 1 MiB
    float* vm  = (float*)(base + (size_t)2 * (1 << 20));          // 1 MiB
    float* kmT = (float*)(base + (size_t)3 * (1 << 20));          // 1 MiB
    int*   idx = (int*)  (base + (size_t)4 * (1 << 20));          // 32 KiB
    float* Ksw = (float*)(base + (size_t)4 * (1 << 20) + (1 << 15));        // 1 MiB
    float* KVc = (float*)(base + (size_t)5 * (1 << 20) + (1 << 15));        // 128 KiB
    float* Ksc = (float*)(base + (size_t)5 * (1 << 20) + (1 << 15) + (1 << 17)); // 4 KiB
    float* KVw = (float*)(base + (size_t)6 * (1 << 20));          // 32 MiB
    u16* kwin  = (u16*)(base + (size_t)40 * (1 << 20));           // 24.5 MiB
    u16* vwin  = (u16*)(base + (size_t)65 * (1 << 20));           // 24.5 MiB
    u16* qwin  = (u16*)(base + (size_t)90 * (1 << 20));           // 24.5 MiB (msg alias)

    k_xform<<<dim3(3 * B * 16 * 2 * 16), dim3(256), 0, stream>>>(
        q, k, v, qwin, kwin, vwin, qm, kmf, vm, kmT);
    k_topk <<<dim3(B * NW), dim3(256), 0, stream>>>(qm, kmT, idx);
    k_kvw  <<<dim3(B * NW * 2), dim3(256), 0, stream>>>(kwin, vwin, KVw, Ksw);
    k_kvc  <<<dim3(B * 2), dim3(256), 0, stream>>>(kmf, vm, KVc, Ksc);
    k_final<<<dim3(B * NW * 2), dim3(256), 0, stream>>>(
        qwin, idx, KVw, Ksw, KVc, Ksc, qwin /* msg aliases qwin, disjoint per block */);
    k_out  <<<dim3(B * 16 * 8), dim3(256), 0, stream>>>(qwin, out);
}

// Round 4
// 319.186 us; speedup vs baseline: 1.2626x; 1.1953x over previous
//
#include <hip/hip_runtime.h>
#include <float.h>

#define B 4
#define D 256
#define HH 112
#define WW 112
#define WS 7
#define NW 256
#define LL 49
#define LP 56      // padded l-dim (u16): 112 B per (win,c) row, 16-B aligned
#define TOPK 8
#define NH 8
#define DH 32
#define STK 60     // k_kvw LDS row stride (u16): conflict-free for 4-row groups

typedef unsigned short u16;
typedef unsigned int u32;

__device__ __forceinline__ float elu1(float x) {
    return x > 0.f ? x + 1.f : __expf(x);
}
__device__ __forceinline__ float bf2f(u16 u) {
    return __uint_as_float(((u32)u) << 16);
}
__device__ __forceinline__ u16 f2bf(float x) {
    u32 u = __float_as_uint(x);
    u32 r = (u + 0x7FFFu + ((u >> 16) & 1u)) >> 16;
    return (u16)r;
}
__device__ __forceinline__ float bflo(u32 w) { return __uint_as_float(w << 16); }
__device__ __forceinline__ float bfhi(u32 w) { return __uint_as_float(w & 0xffff0000u); }

// ---------------------------------------------------------------------------
// K0: windowize one tensor -> bf16 [b][win][c][LP] (+elu for q,k; l>=49 -> 0)
// + fp32 window means. Block = (ti, b, wi, cg8). Reads: 3136-B contiguous
// per channel strip. Writes: 896-B contiguous per window.
// ---------------------------------------------------------------------------
__global__ __launch_bounds__(256) void k_xform(
        const float* __restrict__ q, const float* __restrict__ k,
        const float* __restrict__ v,
        u16* __restrict__ qwin, u16* __restrict__ kwin, u16* __restrict__ vwin,
        float* __restrict__ qm, float* __restrict__ kmf,
        float* __restrict__ vm, float* __restrict__ kmT) {
    __shared__ float stage[8 * 788];   // 8 ch x 784 (7 rows x 112) = 25216 B
    int blk = blockIdx.x;
    int cg = blk & 31, wi = (blk >> 5) & 15, b = (blk >> 9) & 3, ti = blk >> 11;
    int c0 = cg * 8;
    int t = threadIdx.x;
    const float* src = ti == 0 ? q : (ti == 1 ? k : v);
    u16* dst = ti == 0 ? qwin : (ti == 1 ? kwin : vwin);

    // phase A: fully-contiguous reads (7 rows = 3136 B per channel)
    for (int p = t; p < 1568; p += 256) {
        int c = p / 196;
        int i4 = (p - c * 196) * 4;
        const float* gp = src + (size_t)(b * D + c0 + c) * (HH * WW) + wi * 784 + i4;
        *(float4*)&stage[c * 788 + i4] = *(const float4*)gp;
    }
    __syncthreads();

    // phase B: fp32 window means, thread (c, wj) owns one window
    if (t < 128) {
        int c = t >> 4, wjl = t & 15;
        int base = c * 788 + wjl * 7;
        float s = 0.f;
        for (int r = 0; r < WS; ++r)
            for (int x = 0; x < WS; ++x)
                s += stage[base + r * 112 + x];
        float mean = s * (1.f / 49.f);
        int C = c0 + c;
        int win = wi * 16 + wjl;
        if (ti == 0) qm[(size_t)(b * NW + win) * D + C] = mean;
        else if (ti == 1) {
            kmf[(size_t)(b * NW + win) * D + C] = elu1(mean);
            kmT[(size_t)(b * D + C) * NW + win] = mean;
        } else vm[(size_t)(b * NW + win) * D + C] = mean;
    }
    __syncthreads();

    // phase C: channel-major bf16 window write (elu applied for q,k)
    for (int p = t; p < 896; p += 256) {      // 16 win x 8 c x 7 uint4
        int wjl = p / 56;
        int rem = p - wjl * 56;
        int c = rem / 7, j = rem % 7;
        u16 vals[8];
        for (int i = 0; i < 8; ++i) {
            int l = j * 8 + i;
            if (l < LL) {
                int r = l / 7, x = l - r * 7;
                float f = stage[c * 788 + r * 112 + wjl * 7 + x];
                if (ti < 2) f = elu1(f);
                vals[i] = f2bf(f);
            } else vals[i] = 0;               // exact zero pad (feeds ks!)
        }
        int win = wi * 16 + wjl;
        u16* gp = dst + ((size_t)(b * NW + win) * D + c0 + c) * LP + j * 8;
        *(uint4*)gp = make_uint4(
            ((u32)vals[1] << 16) | vals[0], ((u32)vals[3] << 16) | vals[2],
            ((u32)vals[5] << 16) | vals[4], ((u32)vals[7] << 16) | vals[6]);
    }
}

// ---------------------------------------------------------------------------
// K2: sim row + top-8 via wave shuffle argmax (tie -> smaller index).
// ---------------------------------------------------------------------------
__global__ __launch_bounds__(256) void k_topk(
        const float* __restrict__ qm, const float* __restrict__ kmT,
        int* __restrict__ idx) {
    __shared__ float qrow[D];
    __shared__ float cval[4];
    __shared__ int cidx[4];
    __shared__ int winner;
    int b = blockIdx.x >> 8;
    int qw = blockIdx.x & 255;
    int t = threadIdx.x;
    qrow[t] = qm[(size_t)(b * NW + qw) * D + t];
    __syncthreads();
    const float* kb = kmT + (size_t)b * D * NW + t;
    float a0 = 0.f, a1 = 0.f, a2 = 0.f, a3 = 0.f;
    for (int d = 0; d < D; d += 4) {
        a0 += qrow[d]     * kb[(size_t)d * NW];
        a1 += qrow[d + 1] * kb[(size_t)(d + 1) * NW];
        a2 += qrow[d + 2] * kb[(size_t)(d + 2) * NW];
        a3 += qrow[d + 3] * kb[(size_t)(d + 3) * NW];
    }
    float val = (a0 + a1) + (a2 + a3);
    for (int sel = 0; sel < TOPK; ++sel) {
        float v = val; int ii = t;
        for (int off = 32; off > 0; off >>= 1) {
            float ov = __shfl_xor(v, off);
            int oi = __shfl_xor(ii, off);
            if (ov > v || (ov == v && oi < ii)) { v = ov; ii = oi; }
        }
        if ((t & 63) == 0) { cval[t >> 6] = v; cidx[t >> 6] = ii; }
        __syncthreads();
        if (t == 0) {
            float bv = cval[0]; int bi = cidx[0];
            for (int w = 1; w < 4; ++w)
                if (cval[w] > bv || (cval[w] == bv && cidx[w] < bi)) {
                    bv = cval[w]; bi = cidx[w];
                }
            idx[(size_t)(b * NW + qw) * TOPK + sel] = bi;
            winner = bi;
        }
        __syncthreads();
        if (t == winner) val = -FLT_MAX;
    }
}

// ---------------------------------------------------------------------------
// K3: blocks [0,2048): per-(b,win,half) KVw(bf16)[h][32][32] + Ksw(f32) from
// row-dot-products over l. Fully-contiguous 14-KB global reads.
// Blocks [2048,2056): coarse KV over 256 fp32 mean tokens.
// ---------------------------------------------------------------------------
__global__ __launch_bounds__(256) void k_kvw(
        const u16* __restrict__ kwin, const u16* __restrict__ vwin,
        const float* __restrict__ kmf, const float* __restrict__ vm,
        u16* __restrict__ KVw, float* __restrict__ Ksw,
        float* __restrict__ KVc, float* __restrict__ Ksc) {
    __shared__ u16 kf[128 * STK];   // 15360 B
    __shared__ u16 vf[128 * STK];
    int blk = blockIdx.x;
    int t = threadIdx.x;
    if (blk >= B * NW * 2) {
        // ---- coarse KV (fp32 path) ----
        int blkc = blk - B * NW * 2;
        int b = blkc >> 1, half = blkc & 1;
        int h2 = t >> 6, q64 = t & 63, ddq = q64 >> 3, dvq = q64 & 7;
        int ca = half * 128 + h2 * 32 + ddq * 4;
        int cb = half * 128 + h2 * 32 + dvq * 4;
        const float* kb = kmf + (size_t)b * NW * D;
        const float* vb = vm + (size_t)b * NW * D;
        float acc[4][4] = {};
        float ks[4] = {};
        for (int n = 0; n < NW; ++n) {
            float4 a  = *(const float4*)&kb[n * D + ca];
            float4 bv = *(const float4*)&vb[n * D + cb];
            float av[4] = {a.x, a.y, a.z, a.w};
            float bw[4] = {bv.x, bv.y, bv.z, bv.w};
            ks[0] += av[0]; ks[1] += av[1]; ks[2] += av[2]; ks[3] += av[3];
            for (int i = 0; i < 4; ++i)
                for (int j = 0; j < 4; ++j)
                    acc[i][j] += av[i] * bw[j];
        }
        int h = half * 4 + h2;
        size_t obase = (size_t)(b * NH + h) * (DH * DH);
        for (int i = 0; i < 4; ++i) {
            float4 o = {acc[i][0], acc[i][1], acc[i][2], acc[i][3]};
            *(float4*)&KVc[obase + (size_t)(ddq * 4 + i) * DH + dvq * 4] = o;
        }
        if (dvq == 0) {
            float4 o = {ks[0], ks[1], ks[2], ks[3]};
            *(float4*)&Ksc[(size_t)(b * NH + h) * DH + ddq * 4] = o;
        }
        return;
    }
    int b = blk >> 9;
    int win = (blk >> 1) & 255;
    int half = blk & 1;
    const u16* kg = kwin + ((size_t)(b * NW + win) * D + half * 128) * LP;
    const u16* vg = vwin + ((size_t)(b * NW + win) * D + half * 128) * LP;
    // stage 128 rows x 56 u16 -> LDS stride 60 (pads l=56..59 never read)
    for (int p = t; p < 896; p += 256) {
        int c = p / 7, j = p % 7;
        uint4 kq = *(const uint4*)(kg + c * LP + j * 8);
        uint4 vq = *(const uint4*)(vg + c * LP + j * 8);
        *(uint2*)&kf[c * STK + j * 8]     = make_uint2(kq.x, kq.y);
        *(uint2*)&kf[c * STK + j * 8 + 4] = make_uint2(kq.z, kq.w);
        *(uint2*)&vf[c * STK + j * 8]     = make_uint2(vq.x, vq.y);
        *(uint2*)&vf[c * STK + j * 8 + 4] = make_uint2(vq.z, vq.w);
    }
    __syncthreads();
    int h2 = t >> 6, q64 = t & 63, ddq = q64 >> 3, dvq = q64 & 7;
    const u16* ka = kf + (h2 * 32 + ddq * 4) * STK;
    const u16* vb = vf + (h2 * 32 + dvq * 4) * STK;
    float acc[4][4] = {};
    float ks[4] = {};
    for (int l4 = 0; l4 < 14; ++l4) {       // 4 l per iter; l=49..55 are zeros
        float a[4][4], w[4][4];
        for (int i = 0; i < 4; ++i) {
            uint2 kr = *(const uint2*)(ka + i * STK + l4 * 4);
            a[i][0] = bflo(kr.x); a[i][1] = bfhi(kr.x);
            a[i][2] = bflo(kr.y); a[i][3] = bfhi(kr.y);
            uint2 vr = *(const uint2*)(vb + i * STK + l4 * 4);
            w[i][0] = bflo(vr.x); w[i][1] = bfhi(vr.x);
            w[i][2] = bflo(vr.y); w[i][3] = bfhi(vr.y);
        }
        for (int i = 0; i < 4; ++i) {
            ks[i] += (a[i][0] + a[i][1]) + (a[i][2] + a[i][3]);
            for (int j = 0; j < 4; ++j)
                for (int s = 0; s < 4; ++s)
                    acc[i][j] += a[i][s] * w[j][s];
        }
    }
    int h = half * 4 + h2;
    u16* ob = KVw + (size_t)((b * NW + win) * NH + h) * (DH * DH);
    for (int i = 0; i < 4; ++i) {
        u32 p0 = ((u32)f2bf(acc[i][1]) << 16) | f2bf(acc[i][0]);
        u32 p1 = ((u32)f2bf(acc[i][3]) << 16) | f2bf(acc[i][2]);
        *(uint2*)(ob + (ddq * 4 + i) * DH + dvq * 4) = make_uint2(p0, p1);
    }
    if (dvq == 0) {
        float4 o = {ks[0], ks[1], ks[2], ks[3]};
        *(float4*)&Ksw[(size_t)((b * NW + win) * NH + h) * DH + ddq * 4] = o;
    }
}

// ---------------------------------------------------------------------------
// K4: gather-sum KV (bf16 KVw + fp32 coarse), apply Qf, write msg rows
// directly from registers (channel-major, aliases qwin). XCD swizzle.
// ---------------------------------------------------------------------------
__global__ __launch_bounds__(256) void k_final(
        const u16* qwin, const int* __restrict__ idx,
        const u16* __restrict__ KVw, const float* __restrict__ Ksw,
        const float* __restrict__ KVc, const float* __restrict__ Ksc,
        u16* msg) {
    __shared__ float kv[4 * DH * DH];   // 16 KB
    __shared__ float ksl[4 * DH];
    __shared__ u16 qf[128 * LP];        // 14336 B, exact copy of global layout
    __shared__ int idxl[TOPK];
    int blk = blockIdx.x;
    int lin = ((blk & 7) << 8) | (blk >> 3);   // XCD swizzle
    int half = lin & 1;
    int qw = (lin >> 1) & 255;
    int b = lin >> 9;
    int t = threadIdx.x;
    if (t < TOPK) idxl[t] = idx[(size_t)(b * NW + qw) * TOPK + t];
    const u16* qg = qwin + ((size_t)(b * NW + qw) * D + half * 128) * LP;
    for (int p = t; p < 896; p += 256)
        *(uint4*)&qf[p * 8] = *(const uint4*)(qg + p * 8);
    __syncthreads();
    // phase 1: KV = coarse + sum of 8 gathered (bf16) KVw ; same for Ksum
    {
        int h2 = t >> 6;
        int dd = (t & 63) >> 1;
        int dvh = t & 1;
        int h = half * 4 + h2;
        float kvacc[16] = {};
        float ksacc = 0.f;
        for (int s = 0; s < TOPK; ++s) {
            int srcw = idxl[s];
            const u16* rp = KVw + (size_t)((b * NW + srcw) * NH + h) * (DH * DH)
                            + dd * DH + dvh * 16;
            uint4 r0 = *(const uint4*)rp;
            uint4 r1 = *(const uint4*)(rp + 8);
            u32 wsv[4] = {r0.x, r0.y, r0.z, r0.w};
            for (int h4 = 0; h4 < 4; ++h4) {
                kvacc[h4 * 2]     += bflo(wsv[h4]);
                kvacc[h4 * 2 + 1] += bfhi(wsv[h4]);
            }
            u32 wsv1[4] = {r1.x, r1.y, r1.z, r1.w};
            for (int h4 = 0; h4 < 4; ++h4) {
                kvacc[8 + h4 * 2]     += bflo(wsv1[h4]);
                kvacc[8 + h4 * 2 + 1] += bfhi(wsv1[h4]);
            }
            ksacc += Ksw[(size_t)((b * NW + srcw) * NH + h) * DH + dd];
        }
        {
            const float* rowp = KVc + (size_t)(b * NH + h) * (DH * DH)
                                + dd * DH + dvh * 16;
            for (int j4 = 0; j4 < 4; ++j4) {
                float4 r4 = *(const float4*)&rowp[j4 * 4];
                kvacc[j4 * 4 + 0] += r4.x; kvacc[j4 * 4 + 1] += r4.y;
                kvacc[j4 * 4 + 2] += r4.z; kvacc[j4 * 4 + 3] += r4.w;
            }
            ksacc += Ksc[(size_t)(b * NH + h) * DH + dd];
        }
        for (int j = 0; j < 16; ++j)
            kv[h2 * (DH * DH) + dd * DH + dvh * 16 + j] = kvacc[j];
        if (dvh == 0) ksl[h2 * DH + dd] = ksacc;
    }
    __syncthreads();
    // phase 2: per (lset, h2, dv): msg rows from registers -> global
    {
        int lset = t >> 7;                // l0 = 0 or 28
        int h2 = (t >> 5) & 3;
        int dv = t & 31;
        int l0 = lset * 28;
        float m[28] = {}, z[28] = {};
        for (int dd = 0; dd < DH; ++dd) {
            float kc = kv[h2 * (DH * DH) + dd * DH + dv];
            float ko = ksl[h2 * DH + dd];
            const u16* qr = qf + (h2 * 32 + dd) * LP + l0;
#pragma unroll
            for (int u = 0; u < 7; ++u) {
                uint2 qq = *(const uint2*)(qr + u * 4);
                float q0 = bflo(qq.x), q1 = bfhi(qq.x);
                float q2 = bflo(qq.y), q3 = bfhi(qq.y);
                m[u * 4 + 0] += q0 * kc; z[u * 4 + 0] += q0 * ko;
                m[u * 4 + 1] += q1 * kc; z[u * 4 + 1] += q1 * ko;
                m[u * 4 + 2] += q2 * kc; z[u * 4 + 2] += q2 * ko;
                m[u * 4 + 3] += q3 * kc; z[u * 4 + 3] += q3 * ko;
            }
        }
        u16 r[28];
#pragma unroll
        for (int l = 0; l < 28; ++l)
            r[l] = f2bf(m[l] / (z[l] + 1e-6f));
        int C = half * 128 + h2 * 32 + dv;
        u16* mg = msg + ((size_t)(b * NW + qw) * D + C) * LP + l0;
        if (lset == 0) {
            for (int u = 0; u < 7; ++u)
                *(uint2*)(mg + u * 4) = make_uint2(
                    ((u32)r[u * 4 + 1] << 16) | r[u * 4],
                    ((u32)r[u * 4 + 3] << 16) | r[u * 4 + 2]);
        } else {
            for (int u = 0; u < 5; ++u)     // l = 28..47
                *(uint2*)(mg + u * 4) = make_uint2(
                    ((u32)r[u * 4 + 1] << 16) | r[u * 4],
                    ((u32)r[u * 4 + 3] << 16) | r[u * 4 + 2]);
            mg[20] = r[20];                 // l = 48
        }
    }
}

// ---------------------------------------------------------------------------
// K5: channel-major msg -> image layout, full-line coalesced writes.
// ---------------------------------------------------------------------------
__global__ __launch_bounds__(256) void k_out(
        const u16* __restrict__ msg, float* __restrict__ out) {
    __shared__ u16 ms[16 * 16 * LP];   // 28672 B
    int blk = blockIdx.x;
    int cg = blk & 15, wi = (blk >> 4) & 15, b = blk >> 8;
    int c0 = cg * 16;
    int t = threadIdx.x;
    for (int p = t; p < 1792; p += 256) {     // 16 win x 16 c x 7 uint4
        int wjl = p / 112;
        int rem = p - wjl * 112;
        int c = rem / 7, j = rem % 7;
        const u16* gp = msg +
            ((size_t)(b * NW + wi * 16 + wjl) * D + c0 + c) * LP + j * 8;
        *(uint4*)&ms[(wjl * 16 + c) * LP + j * 8] = *(const uint4*)gp;
    }
    __syncthreads();
    for (int p = t; p < 3136; p += 256) {     // 16 c x 784 floats / 4
        int c = p / 196;
        int f4 = (p - c * 196) * 4;
        int r = f4 / 112, col = f4 - r * 112;
        float4 o;
        float* op = (float*)&o;
        for (int j = 0; j < 4; ++j) {
            int xg = col + j;
            int wj = xg / 7, x = xg - wj * 7;
            int l = r * 7 + x;
            op[j] = bf2f(ms[(wj * 16 + c) * LP + l]);
        }
        float* gp = out + (size_t)(b * D + c0 + c) * (HH * WW)
                    + (wi * WS + r) * WW + col;
        *(float4*)gp = o;
    }
}

// ---------------------------------------------------------------------------
extern "C" void kernel_launch(void* const* d_in, const int* in_sizes, int n_in,
                              void* d_out, int out_size, void* d_ws, size_t ws_size,
                              hipStream_t stream) {
    const float* q = (const float*)d_in[0];
    const float* k = (const float*)d_in[1];
    const float* v = (const float*)d_in[2];
    float* out = (float*)d_out;
    char* base = (char*)d_ws;

    const size_t MB = 1 << 20;
    float* qm  = (float*)(base);                       // 1 MiB
    float* kmf = (float*)(base + 1 * MB);              // 1 MiB
    float* vm  = (float*)(base + 2 * MB);              // 1 MiB
    float* kmT = (float*)(base + 3 * MB);              // 1 MiB
    int*   idx = (int*)  (base + 4 * MB);              // 32 KiB
    float* Ksw = (float*)(base + 4 * MB + (1 << 15));  // 1 MiB
    float* KVc = (float*)(base + 5 * MB + (1 << 15));  // 128 KiB
    float* Ksc = (float*)(base + 5 * MB + (1 << 15) + (1 << 17)); // 4 KiB
    u16* KVw  = (u16*)(base + 6 * MB);                 // 16 MiB (bf16)
    u16* kwin = (u16*)(base + 24 * MB);                // 28 MiB
    u16* vwin = (u16*)(base + 52 * MB);                // 28 MiB
    u16* qwin = (u16*)(base + 80 * MB);                // 28 MiB (msg alias)
    // total: 108 MiB

    k_xform<<<dim3(3 * B * 16 * 32), dim3(256), 0, stream>>>(
        q, k, v, qwin, kwin, vwin, qm, kmf, vm, kmT);
    k_topk <<<dim3(B * NW), dim3(256), 0, stream>>>(qm, kmT, idx);
    k_kvw  <<<dim3(B * NW * 2 + B * 2), dim3(256), 0, stream>>>(
        kwin, vwin, kmf, vm, KVw, Ksw, KVc, Ksc);
    k_final<<<dim3(B * NW * 2), dim3(256), 0, stream>>>(
        qwin, idx, KVw, Ksw, KVc, Ksc, qwin /* msg aliases qwin per-block */);
    k_out  <<<dim3(B * 16 * 16), dim3(256), 0, stream>>>(qwin, out);
}

// Round 6
// 305.835 us; speedup vs baseline: 1.3177x; 1.0437x over previous
//
#include <hip/hip_runtime.h>
#include <float.h>

#define B 4
#define D 256
#define HH 112
#define WW 112
#define WS 7
#define NW 256
#define LL 49
#define LP 56      // padded l-dim (u16): 112 B per (win,c) row, 16-B aligned
#define TOPK 8
#define NH 8
#define DH 32
#define STK 60     // k_mid kvw LDS row stride (u16)

typedef unsigned short u16;
typedef unsigned int u32;

__device__ __forceinline__ float elu1(float x) {
    return x > 0.f ? x + 1.f : __expf(x);
}
__device__ __forceinline__ float bf2f(u16 u) {
    return __uint_as_float(((u32)u) << 16);
}
__device__ __forceinline__ u16 f2bf(float x) {
    u32 u = __float_as_uint(x);
    u32 r = (u + 0x7FFFu + ((u >> 16) & 1u)) >> 16;
    return (u16)r;
}
__device__ __forceinline__ u32 pack_bf16(float lo, float hi) {
    return ((u32)f2bf(hi) << 16) | f2bf(lo);
}
__device__ __forceinline__ float bflo(u32 w) { return __uint_as_float(w << 16); }
__device__ __forceinline__ float bfhi(u32 w) { return __uint_as_float(w & 0xffff0000u); }

// ---------------------------------------------------------------------------
// K0: windowize one tensor -> bf16 [b][win][c][LP] (+elu for q,k; l>=49 -> 0)
// + fp32 window means. Block = (ti, b, wi, cg4). Transpose-on-write: phase A
// scatters RAW scalars to window-major LDS (means must be of raw values!);
// phase B means (sequential l-order, matches R4-passed rounding); phase C
// applies elu during the vectorized bf16 pack.
// ---------------------------------------------------------------------------
__global__ __launch_bounds__(256) void k_xform(
        const float* __restrict__ q, const float* __restrict__ k,
        const float* __restrict__ v,
        u16* __restrict__ qwin, u16* __restrict__ kwin, u16* __restrict__ vwin,
        float* __restrict__ qm, float* __restrict__ kmf,
        float* __restrict__ vm, float* __restrict__ kmT) {
    __shared__ float st[4 * 16 * LP];   // [c][wj][l(56)] = 14336 B
    int blk = blockIdx.x;
    int cg = blk & 63, wi = (blk >> 6) & 15, b = (blk >> 10) & 3, ti = blk >> 12;
    int c0 = cg * 4;
    int t = threadIdx.x;
    const float* src = ti == 0 ? q : (ti == 1 ? k : v);
    u16* dst = ti == 0 ? qwin : (ti == 1 ? kwin : vwin);

    // zero the l=49..55 pad (disjoint from phase-A writes)
    if (t < 448) {
        int c = t / 112, rem = t - c * 112;
        int wj = rem / 7, pl = rem - wj * 7;
        st[(c * 16 + wj) * LP + 49 + pl] = 0.f;
    }
    // phase A: contiguous float4 reads; RAW scalar scatter to window-major
    for (int p = t; p < 784; p += 256) {
        int c = p / 196;
        int i4 = (p - c * 196) * 4;
        int r = i4 / 112, x0 = i4 - r * 112;
        const float* gp = src + (size_t)(b * D + c0 + c) * (HH * WW) + wi * 784 + i4;
        float4 f = *(const float4*)gp;
        float vals[4] = {f.x, f.y, f.z, f.w};
        int base = c * (16 * LP) + r * 7;
#pragma unroll
        for (int j = 0; j < 4; ++j) {
            int x = x0 + j;
            int wj = (x * 9363) >> 16;          // x/7, exact for x<112
            st[base + wj * 49 + x] = vals[j];   // wj*56 + (x-wj*7) == wj*49+x
        }
    }
    __syncthreads();
    // phase B: fp32 means of RAW values, sequential l-order (R4 rounding)
    if (t < 64) {
        int c = t >> 4, wj = t & 15;
        const float* row = st + (c * 16 + wj) * LP;
        float s = 0.f;
        for (int l = 0; l < LL; ++l) s += row[l];
        float mean = s * (1.f / 49.f);
        int C = c0 + c;
        int win = wi * 16 + wj;
        if (ti == 0) qm[(size_t)(b * NW + win) * D + C] = mean;
        else if (ti == 1) {
            kmf[(size_t)(b * NW + win) * D + C] = elu1(mean);
            kmT[(size_t)(b * D + C) * NW + win] = mean;
        } else vm[(size_t)(b * NW + win) * D + C] = mean;
    }
    // phase C: vector LDS reads -> elu (q,k) -> packed bf16 -> contiguous
    for (int p = t; p < 448; p += 256) {
        int wj = p / 28;
        int rem = p - wj * 28;
        int c = rem / 7, j = rem - c * 7;
        const float* row = st + (c * 16 + wj) * LP + j * 8;
        float4 f0 = *(const float4*)row;
        float4 f1 = *(const float4*)(row + 4);
        if (ti < 2) {
            f0.x = elu1(f0.x); f0.y = elu1(f0.y);
            f0.z = elu1(f0.z); f0.w = elu1(f0.w);
            f1.x = elu1(f1.x); f1.y = elu1(f1.y);
            f1.z = elu1(f1.z); f1.w = elu1(f1.w);
            if (j == 6) { // l=49..55 pad: elu1(0)=1, must stay 0
                f0.y = 0.f; f0.z = 0.f; f0.w = 0.f;
                f1.x = 0.f; f1.y = 0.f; f1.z = 0.f; f1.w = 0.f;
            }
        }
        uint4 o = make_uint4(pack_bf16(f0.x, f0.y), pack_bf16(f0.z, f0.w),
                             pack_bf16(f1.x, f1.y), pack_bf16(f1.z, f1.w));
        int win = wi * 16 + wj;
        u16* gp = dst + ((size_t)(b * NW + win) * D + c0 + c) * LP + j * 8;
        *(uint4*)gp = o;
    }
}

// ---------------------------------------------------------------------------
// K_mid: fused. Blocks [0,1024): top-8 selection. [1024,3072): per-(b,win,
// half) KVw(bf16)+Ksw. [3072,3080): coarse KV over mean tokens.
// ---------------------------------------------------------------------------
__global__ __launch_bounds__(256) void k_mid(
        const u16* __restrict__ kwin, const u16* __restrict__ vwin,
        const float* __restrict__ qm, const float* __restrict__ kmT,
        const float* __restrict__ kmf, const float* __restrict__ vm,
        int* __restrict__ idx,
        u16* __restrict__ KVw, float* __restrict__ Ksw,
        float* __restrict__ KVc, float* __restrict__ Ksc) {
    __shared__ u16 kf[128 * STK];   // 15360 B
    __shared__ u16 vf[128 * STK];
    int blk = blockIdx.x;
    int t = threadIdx.x;
    if (blk < B * NW) {
        // ---- top-k ----
        float* qrow = (float*)kf;              // 256 floats
        float* cval = qrow + 256;              // 4
        int* cidx = (int*)(qrow + 260);        // 4
        int* winner = cidx + 4;
        int b = blk >> 8;
        int qw = blk & 255;
        qrow[t] = qm[(size_t)(b * NW + qw) * D + t];
        __syncthreads();
        const float* kb = kmT + (size_t)b * D * NW + t;
        float a0 = 0.f, a1 = 0.f, a2 = 0.f, a3 = 0.f;
        for (int d = 0; d < D; d += 4) {
            a0 += qrow[d]     * kb[(size_t)d * NW];
            a1 += qrow[d + 1] * kb[(size_t)(d + 1) * NW];
            a2 += qrow[d + 2] * kb[(size_t)(d + 2) * NW];
            a3 += qrow[d + 3] * kb[(size_t)(d + 3) * NW];
        }
        float val = (a0 + a1) + (a2 + a3);
        for (int sel = 0; sel < TOPK; ++sel) {
            float vv = val; int ii = t;
            for (int off = 32; off > 0; off >>= 1) {
                float ov = __shfl_xor(vv, off);
                int oi = __shfl_xor(ii, off);
                if (ov > vv || (ov == vv && oi < ii)) { vv = ov; ii = oi; }
            }
            if ((t & 63) == 0) { cval[t >> 6] = vv; cidx[t >> 6] = ii; }
            __syncthreads();
            if (t == 0) {
                float bv = cval[0]; int bi = cidx[0];
                for (int w = 1; w < 4; ++w)
                    if (cval[w] > bv || (cval[w] == bv && cidx[w] < bi)) {
                        bv = cval[w]; bi = cidx[w];
                    }
                idx[(size_t)(b * NW + qw) * TOPK + sel] = bi;
                *winner = bi;
            }
            __syncthreads();
            if (t == *winner) val = -FLT_MAX;
        }
        return;
    }
    if (blk >= B * NW + B * NW * 2) {
        // ---- coarse KV (fp32 path) ----
        int blkc = blk - (B * NW + B * NW * 2);
        int b = blkc >> 1, half = blkc & 1;
        int h2 = t >> 6, q64 = t & 63, ddq = q64 >> 3, dvq = q64 & 7;
        int ca = half * 128 + h2 * 32 + ddq * 4;
        int cb = half * 128 + h2 * 32 + dvq * 4;
        const float* kb = kmf + (size_t)b * NW * D;
        const float* vb = vm + (size_t)b * NW * D;
        float acc[4][4] = {};
        float ks[4] = {};
        for (int n = 0; n < NW; ++n) {
            float4 a  = *(const float4*)&kb[n * D + ca];
            float4 bv = *(const float4*)&vb[n * D + cb];
            float av[4] = {a.x, a.y, a.z, a.w};
            float bw[4] = {bv.x, bv.y, bv.z, bv.w};
            ks[0] += av[0]; ks[1] += av[1]; ks[2] += av[2]; ks[3] += av[3];
            for (int i = 0; i < 4; ++i)
                for (int j = 0; j < 4; ++j)
                    acc[i][j] += av[i] * bw[j];
        }
        int h = half * 4 + h2;
        size_t obase = (size_t)(b * NH + h) * (DH * DH);
        for (int i = 0; i < 4; ++i) {
            float4 o = {acc[i][0], acc[i][1], acc[i][2], acc[i][3]};
            *(float4*)&KVc[obase + (size_t)(ddq * 4 + i) * DH + dvq * 4] = o;
        }
        if (dvq == 0) {
            float4 o = {ks[0], ks[1], ks[2], ks[3]};
            *(float4*)&Ksc[(size_t)(b * NH + h) * DH + ddq * 4] = o;
        }
        return;
    }
    // ---- per-window KV ----
    int blkw = blk - B * NW;
    int b = blkw >> 9;
    int win = (blkw >> 1) & 255;
    int half = blkw & 1;
    const u16* kg = kwin + ((size_t)(b * NW + win) * D + half * 128) * LP;
    const u16* vg = vwin + ((size_t)(b * NW + win) * D + half * 128) * LP;
    for (int p = t; p < 896; p += 256) {
        int c = p / 7, j = p % 7;
        uint4 kq = *(const uint4*)(kg + c * LP + j * 8);
        uint4 vq = *(const uint4*)(vg + c * LP + j * 8);
        *(uint2*)&kf[c * STK + j * 8]     = make_uint2(kq.x, kq.y);
        *(uint2*)&kf[c * STK + j * 8 + 4] = make_uint2(kq.z, kq.w);
        *(uint2*)&vf[c * STK + j * 8]     = make_uint2(vq.x, vq.y);
        *(uint2*)&vf[c * STK + j * 8 + 4] = make_uint2(vq.z, vq.w);
    }
    __syncthreads();
    int h2 = t >> 6, q64 = t & 63, ddq = q64 >> 3, dvq = q64 & 7;
    const u16* ka = kf + (h2 * 32 + ddq * 4) * STK;
    const u16* vb = vf + (h2 * 32 + dvq * 4) * STK;
    float acc[4][4] = {};
    float ks[4] = {};
    for (int l4 = 0; l4 < 14; ++l4) {
        float a[4][4], w[4][4];
        for (int i = 0; i < 4; ++i) {
            uint2 kr = *(const uint2*)(ka + i * STK + l4 * 4);
            a[i][0] = bflo(kr.x); a[i][1] = bfhi(kr.x);
            a[i][2] = bflo(kr.y); a[i][3] = bfhi(kr.y);
            uint2 vr = *(const uint2*)(vb + i * STK + l4 * 4);
            w[i][0] = bflo(vr.x); w[i][1] = bfhi(vr.x);
            w[i][2] = bflo(vr.y); w[i][3] = bfhi(vr.y);
        }
        for (int i = 0; i < 4; ++i) {
            ks[i] += (a[i][0] + a[i][1]) + (a[i][2] + a[i][3]);
            for (int j = 0; j < 4; ++j)
                for (int s = 0; s < 4; ++s)
                    acc[i][j] += a[i][s] * w[j][s];
        }
    }
    int h = half * 4 + h2;
    u16* ob = KVw + (size_t)((b * NW + win) * NH + h) * (DH * DH);
    for (int i = 0; i < 4; ++i) {
        u32 p0 = pack_bf16(acc[i][0], acc[i][1]);
        u32 p1 = pack_bf16(acc[i][2], acc[i][3]);
        *(uint2*)(ob + (ddq * 4 + i) * DH + dvq * 4) = make_uint2(p0, p1);
    }
    if (dvq == 0) {
        float4 o = {ks[0], ks[1], ks[2], ks[3]};
        *(float4*)&Ksw[(size_t)((b * NW + win) * NH + h) * DH + ddq * 4] = o;
    }
}

// ---------------------------------------------------------------------------
// K4: gather-sum KV (bf16 KVw + fp32 coarse), apply Qf, write msg rows
// directly from registers (channel-major, aliases qwin). XCD swizzle.
// ---------------------------------------------------------------------------
__global__ __launch_bounds__(256) void k_final(
        const u16* qwin, const int* __restrict__ idx,
        const u16* __restrict__ KVw, const float* __restrict__ Ksw,
        const float* __restrict__ KVc, const float* __restrict__ Ksc,
        u16* msg) {
    __shared__ float kv[4 * DH * DH];   // 16 KB
    __shared__ float ksl[4 * DH];
    __shared__ u16 qf[128 * LP];        // 14336 B
    __shared__ int idxl[TOPK];
    int blk = blockIdx.x;
    int lin = ((blk & 7) << 8) | (blk >> 3);   // XCD swizzle
    int half = lin & 1;
    int qw = (lin >> 1) & 255;
    int b = lin >> 9;
    int t = threadIdx.x;
    if (t < TOPK) idxl[t] = idx[(size_t)(b * NW + qw) * TOPK + t];
    const u16* qg = qwin + ((size_t)(b * NW + qw) * D + half * 128) * LP;
    for (int p = t; p < 896; p += 256)
        *(uint4*)&qf[p * 8] = *(const uint4*)(qg + p * 8);
    __syncthreads();
    {
        int h2 = t >> 6;
        int dd = (t & 63) >> 1;
        int dvh = t & 1;
        int h = half * 4 + h2;
        float kvacc[16] = {};
        float ksacc = 0.f;
        for (int s = 0; s < TOPK; ++s) {
            int srcw = idxl[s];
            const u16* rp = KVw + (size_t)((b * NW + srcw) * NH + h) * (DH * DH)
                            + dd * DH + dvh * 16;
            uint4 r0 = *(const uint4*)rp;
            uint4 r1 = *(const uint4*)(rp + 8);
            u32 wsv[4] = {r0.x, r0.y, r0.z, r0.w};
            for (int h4 = 0; h4 < 4; ++h4) {
                kvacc[h4 * 2]     += bflo(wsv[h4]);
                kvacc[h4 * 2 + 1] += bfhi(wsv[h4]);
            }
            u32 wsv1[4] = {r1.x, r1.y, r1.z, r1.w};
            for (int h4 = 0; h4 < 4; ++h4) {
                kvacc[8 + h4 * 2]     += bflo(wsv1[h4]);
                kvacc[8 + h4 * 2 + 1] += bfhi(wsv1[h4]);
            }
            ksacc += Ksw[(size_t)((b * NW + srcw) * NH + h) * DH + dd];
        }
        {
            const float* rowp = KVc + (size_t)(b * NH + h) * (DH * DH)
                                + dd * DH + dvh * 16;
            for (int j4 = 0; j4 < 4; ++j4) {
                float4 r4 = *(const float4*)&rowp[j4 * 4];
                kvacc[j4 * 4 + 0] += r4.x; kvacc[j4 * 4 + 1] += r4.y;
                kvacc[j4 * 4 + 2] += r4.z; kvacc[j4 * 4 + 3] += r4.w;
            }
            ksacc += Ksc[(size_t)(b * NH + h) * DH + dd];
        }
        for (int j = 0; j < 16; ++j)
            kv[h2 * (DH * DH) + dd * DH + dvh * 16 + j] = kvacc[j];
        if (dvh == 0) ksl[h2 * DH + dd] = ksacc;
    }
    __syncthreads();
    {
        int lset = t >> 7;                // l0 = 0 or 28
        int h2 = (t >> 5) & 3;
        int dv = t & 31;
        int l0 = lset * 28;
        float m[28] = {}, z[28] = {};
        for (int dd = 0; dd < DH; ++dd) {
            float kc = kv[h2 * (DH * DH) + dd * DH + dv];
            float ko = ksl[h2 * DH + dd];
            const u16* qr = qf + (h2 * 32 + dd) * LP + l0;
#pragma unroll
            for (int u = 0; u < 7; ++u) {
                uint2 qq = *(const uint2*)(qr + u * 4);
                float q0 = bflo(qq.x), q1 = bfhi(qq.x);
                float q2 = bflo(qq.y), q3 = bfhi(qq.y);
                m[u * 4 + 0] += q0 * kc; z[u * 4 + 0] += q0 * ko;
                m[u * 4 + 1] += q1 * kc; z[u * 4 + 1] += q1 * ko;
                m[u * 4 + 2] += q2 * kc; z[u * 4 + 2] += q2 * ko;
                m[u * 4 + 3] += q3 * kc; z[u * 4 + 3] += q3 * ko;
            }
        }
        u16 r[28];
#pragma unroll
        for (int l = 0; l < 28; ++l)
            r[l] = f2bf(m[l] / (z[l] + 1e-6f));
        int C = half * 128 + h2 * 32 + dv;
        u16* mg = msg + ((size_t)(b * NW + qw) * D + C) * LP + l0;
        if (lset == 0) {
            for (int u = 0; u < 7; ++u)
                *(uint2*)(mg + u * 4) = make_uint2(
                    ((u32)r[u * 4 + 1] << 16) | r[u * 4],
                    ((u32)r[u * 4 + 3] << 16) | r[u * 4 + 2]);
        } else {
            for (int u = 0; u < 5; ++u)
                *(uint2*)(mg + u * 4) = make_uint2(
                    ((u32)r[u * 4 + 1] << 16) | r[u * 4],
                    ((u32)r[u * 4 + 3] << 16) | r[u * 4 + 2]);
            mg[20] = r[20];
        }
    }
}

// ---------------------------------------------------------------------------
// K5: channel-major msg -> image layout, full-line coalesced writes.
// ---------------------------------------------------------------------------
__global__ __launch_bounds__(256) void k_out(
        const u16* __restrict__ msg, float* __restrict__ out) {
    __shared__ u16 ms[16 * 16 * LP];   // 28672 B
    int blk = blockIdx.x;
    int cg = blk & 15, wi = (blk >> 4) & 15, b = blk >> 8;
    int c0 = cg * 16;
    int t = threadIdx.x;
    for (int p = t; p < 1792; p += 256) {
        int wjl = p / 112;
        int rem = p - wjl * 112;
        int c = rem / 7, j = rem % 7;
        const u16* gp = msg +
            ((size_t)(b * NW + wi * 16 + wjl) * D + c0 + c) * LP + j * 8;
        *(uint4*)&ms[(wjl * 16 + c) * LP + j * 8] = *(const uint4*)gp;
    }
    __syncthreads();
    for (int p = t; p < 3136; p += 256) {
        int c = p / 196;
        int f4 = (p - c * 196) * 4;
        int r = f4 / 112, col = f4 - r * 112;
        float4 o;
        float* op = (float*)&o;
        for (int j = 0; j < 4; ++j) {
            int xg = col + j;
            int wj = xg / 7, x = xg - wj * 7;
            int l = r * 7 + x;
            op[j] = bf2f(ms[(wj * 16 + c) * LP + l]);
        }
        float* gp = out + (size_t)(b * D + c0 + c) * (HH * WW)
                    + (wi * WS + r) * WW + col;
        *(float4*)gp = o;
    }
}

// ---------------------------------------------------------------------------
extern "C" void kernel_launch(void* const* d_in, const int* in_sizes, int n_in,
                              void* d_out, int out_size, void* d_ws, size_t ws_size,
                              hipStream_t stream) {
    const float* q = (const float*)d_in[0];
    const float* k = (const float*)d_in[1];
    const float* v = (const float*)d_in[2];
    float* out = (float*)d_out;
    char* base = (char*)d_ws;

    const size_t MB = 1 << 20;
    float* qm  = (float*)(base);                       // 1 MiB
    float* kmf = (float*)(base + 1 * MB);              // 1 MiB
    float* vm  = (float*)(base + 2 * MB);              // 1 MiB
    float* kmT = (float*)(base + 3 * MB);              // 1 MiB
    int*   idx = (int*)  (base + 4 * MB);              // 32 KiB
    float* Ksw = (float*)(base + 4 * MB + (1 << 15));  // 1 MiB
    float* KVc = (float*)(base + 5 * MB + (1 << 15));  // 128 KiB
    float* Ksc = (float*)(base + 5 * MB + (1 << 15) + (1 << 17)); // 4 KiB
    u16* KVw  = (u16*)(base + 6 * MB);                 // 16 MiB (bf16)
    u16* kwin = (u16*)(base + 24 * MB);                // 28 MiB
    u16* vwin = (u16*)(base + 52 * MB);                // 28 MiB
    u16* qwin = (u16*)(base + 80 * MB);                // 28 MiB (msg alias)

    k_xform<<<dim3(3 * B * 16 * 64), dim3(256), 0, stream>>>(
        q, k, v, qwin, kwin, vwin, qm, kmf, vm, kmT);
    k_mid  <<<dim3(B * NW + B * NW * 2 + B * 2), dim3(256), 0, stream>>>(
        kwin, vwin, qm, kmT, kmf, vm, idx, KVw, Ksw, KVc, Ksc);
    k_final<<<dim3(B * NW * 2), dim3(256), 0, stream>>>(
        qwin, idx, KVw, Ksw, KVc, Ksc, qwin /* msg aliases qwin per-block */);
    k_out  <<<dim3(B * 16 * 16), dim3(256), 0, stream>>>(qwin, out);
}